// Round 1
// baseline (210.474 us; speedup 1.0000x reference)
//
#include <hip/hip_runtime.h>
#include <stdint.h>
#include <math.h>

#define B_   2
#define S_   2048
#define D_   1024
#define H_   16
#define HD_  64
#define M_   (B_*S_)     // 4096
#define N3_  (3*D_)      // 3072

typedef __bf16 bf16;
typedef __bf16 bf16x4v __attribute__((ext_vector_type(4)));
typedef __bf16 bf16x8 __attribute__((ext_vector_type(8)));
typedef float  f32x4 __attribute__((ext_vector_type(4)));

__device__ __forceinline__ void gload_lds16(const void* g, void* l) {
  __builtin_amdgcn_global_load_lds(
      (__attribute__((address_space(1))) const unsigned int*)g,
      (__attribute__((address_space(3))) unsigned int*)l, 16, 0, 0);
}

// ---------------- convert x fp32 -> bf16 ----------------
__global__ __launch_bounds__(256) void conv_f32_bf16(const float* __restrict__ in,
                                                     bf16* __restrict__ out, int n4) {
  int i = blockIdx.x * 256 + threadIdx.x;
  if (i < n4) {
    float4 v = ((const float4*)in)[i];
    bf16x4v o;
    o[0] = (bf16)v.x; o[1] = (bf16)v.y; o[2] = (bf16)v.z; o[3] = (bf16)v.w;
    *(bf16x4v*)(out + (size_t)i * 4) = o;
  }
}

// ---------------- transpose fp32 [R][C] -> bf16 [C][R] ----------------
__global__ __launch_bounds__(256) void transpose_to_bf16(const float* __restrict__ in,
                                                         bf16* __restrict__ out, int R, int C) {
  __shared__ bf16 tile[32][33];
  int c0 = blockIdx.x * 32, r0 = blockIdx.y * 32;
  int tx = threadIdx.x, ty = threadIdx.y;   // 32 x 8
  for (int j = 0; j < 4; j++) {
    int r = r0 + ty + j * 8;
    tile[ty + j * 8][tx] = (bf16)in[(size_t)r * C + c0 + tx];
  }
  __syncthreads();
  for (int j = 0; j < 4; j++) {
    int c = c0 + ty + j * 8;
    out[(size_t)c * R + r0 + tx] = tile[tx][ty + j * 8];
  }
}

// ---------------- RoPE table ----------------
__global__ __launch_bounds__(256) void rope_table(float* __restrict__ cosT, float* __restrict__ sinT) {
  int i = blockIdx.x * 256 + threadIdx.x;   // < 2048*32
  int s = i >> 5, d = i & 31;
  float inv = powf(10000.0f, -(float)d * (1.0f / 32.0f));
  float a = (float)s * inv;
  float sv, cv;
  sincosf(a, &sv, &cv);
  cosT[i] = cv; sinT[i] = sv;
}

// ---------------- RoPE apply (in place on q,k parts of qkv) ----------------
__global__ __launch_bounds__(256) void rope_apply(bf16* __restrict__ qkv,
                                                  const float* __restrict__ cosT,
                                                  const float* __restrict__ sinT) {
  int i = blockIdx.x * 256 + threadIdx.x;   // < B*S*H*32
  int d = i & 31; int r = i >> 5;
  int h = r & 15; r >>= 4;
  int s = r & 2047; int b = r >> 11;
  size_t base = ((size_t)(b * 2048 + s)) * 3072 + h * 64 + d;
  float c = cosT[s * 32 + d], sn = sinT[s * 32 + d];
  float x1 = (float)qkv[base],        x2 = (float)qkv[base + 32];
  qkv[base]        = (bf16)(x1 * c - x2 * sn);
  qkv[base + 32]   = (bf16)(x2 * c + x1 * sn);
  float y1 = (float)qkv[base + 1024], y2 = (float)qkv[base + 1024 + 32];
  qkv[base + 1024]      = (bf16)(y1 * c - y2 * sn);
  qkv[base + 1024 + 32] = (bf16)(y2 * c + y1 * sn);
}

// ---------------- GEMM: C[M][N] = A[M][K] * Bt[N][K]^T ----------------
template<bool OUT_BF16>
__global__ __launch_bounds__(256) void gemm128(const bf16* __restrict__ A,
                                               const bf16* __restrict__ Bt,
                                               int M, int N, int K,
                                               bf16* __restrict__ Cb,
                                               float* __restrict__ Cf,
                                               const float* __restrict__ bias) {
  __shared__ bf16 As[128 * 32];
  __shared__ bf16 Bs[128 * 32];
  int tid = threadIdx.x;
  int lane = tid & 63, w = tid >> 6;
  int m0 = blockIdx.y * 128, n0 = blockIdx.x * 128;
  int m_off = (w >> 1) * 64, n_off = (w & 1) * 64;
  f32x4 acc[4][4] = {};

  const char* Ab = (const char*)A;
  const char* Bb = (const char*)Bt;
  int srow = (lane >> 2);          // 0..15 within segment
  int skb  = (lane & 3) * 16;      // byte offset within 64B row

  for (int k0 = 0; k0 < K; k0 += 32) {
    for (int j = 0; j < 2; j++) {
      int seg = j * 4 + w;
      int row = seg * 16 + srow;
      gload_lds16(Ab + ((size_t)(m0 + row) * K + k0) * 2 + skb, (char*)As + seg * 1024);
      gload_lds16(Bb + ((size_t)(n0 + row) * K + k0) * 2 + skb, (char*)Bs + seg * 1024);
    }
    __syncthreads();
    int rl = lane & 15;
    int kgb = (lane >> 4) * 16;    // k-group byte offset
    bf16x8 a[4], b[4];
    for (int i = 0; i < 4; i++)
      a[i] = *(const bf16x8*)((const char*)As + (m_off + i * 16 + rl) * 64 + kgb);
    for (int i = 0; i < 4; i++)
      b[i] = *(const bf16x8*)((const char*)Bs + (n_off + i * 16 + rl) * 64 + kgb);
    for (int i = 0; i < 4; i++)
      for (int j = 0; j < 4; j++)
        acc[i][j] = __builtin_amdgcn_mfma_f32_16x16x32_bf16(a[i], b[j], acc[i][j], 0, 0, 0);
    __syncthreads();
  }

  int rq = (lane >> 4) * 4, cl = lane & 15;
  for (int i = 0; i < 4; i++)
    for (int j = 0; j < 4; j++) {
      int col = n0 + n_off + j * 16 + cl;
      for (int r = 0; r < 4; r++) {
        int row = m0 + m_off + i * 16 + rq + r;
        float v = acc[i][j][r];
        if constexpr (OUT_BF16) Cb[(size_t)row * N + col] = (bf16)v;
        else                    Cf[(size_t)row * N + col] = v + bias[col];
      }
    }
}

// ---------------- flash attention ----------------
// grid: (B*H, S/128); 256 threads (4 waves); wave w owns 32 q-rows.
__global__ __launch_bounds__(256) void attn_kernel(const bf16* __restrict__ qkv,
                                                   bf16* __restrict__ O) {
  __shared__ __align__(16) unsigned char smem[32768]; // K:0..8K, Vt:8K..16K, P: 16K + w*4K
  int tid = threadIdx.x, lane = tid & 63, w = tid >> 6;
  int bh = blockIdx.x; int b = bh >> 4, h = bh & 15;
  int qt = blockIdx.y;
  int q0w = qt * 128 + w * 32;
  const char* qb = (const char*)qkv;

  int rl = lane & 15, kg = lane >> 4;

  // Q fragments from global (already roped)
  bf16x8 aq[2][2];
  for (int qf = 0; qf < 2; qf++)
    for (int kb = 0; kb < 2; kb++) {
      int row = b * 2048 + q0w + qf * 16 + rl;
      aq[qf][kb] = *(const bf16x8*)(qb + ((size_t)row * 3072 + h * 64 + kb * 32 + kg * 8) * 2);
    }

  f32x4 o[2][4] = {};
  float mrun[2][4], lrun[2][4];
  for (int qf = 0; qf < 2; qf++)
    for (int r = 0; r < 4; r++) { mrun[qf][r] = -__builtin_inff(); lrun[qf][r] = 0.f; }

  int ntiles = 2 * qt + 2;
  for (int t = 0; t < ntiles; t++) {
    int kv0 = t * 64;
    __syncthreads();
    // stage K [64][64] (swizzled) and V^T [64][64] (swizzled)
    for (int shot = 0; shot < 2; shot++) {
      int idx = shot * 256 + tid;
      int rr = idx >> 3, cc = idx & 7;
      size_t grow = ((size_t)(b * 2048 + kv0 + rr)) * 3072;
      bf16x8 kvec = *(const bf16x8*)(qb + (grow + 1024 + h * 64 + cc * 8) * 2);
      *(uint4*)(smem + ((rr * 128 + cc * 16) ^ ((rr & 7) << 4))) = *(const uint4*)&kvec;
      bf16x8 vvec = *(const bf16x8*)(qb + (grow + 2048 + h * 64 + cc * 8) * 2);
      for (int e = 0; e < 8; e++) {
        int d = cc * 8 + e;
        *(bf16*)(smem + 8192 + ((d * 128 + rr * 2) ^ ((d & 7) << 4))) = vvec[e];
      }
    }
    __syncthreads();

    // S = Q K^T
    f32x4 sc[2][4] = {};
    for (int nf = 0; nf < 4; nf++) {
      int c = nf * 16 + rl;
      for (int kb = 0; kb < 2; kb++) {
        bf16x8 bk = *(const bf16x8*)(smem + ((c * 128 + kb * 64 + kg * 16) ^ ((c & 7) << 4)));
        sc[0][nf] = __builtin_amdgcn_mfma_f32_16x16x32_bf16(aq[0][kb], bk, sc[0][nf], 0, 0, 0);
        sc[1][nf] = __builtin_amdgcn_mfma_f32_16x16x32_bf16(aq[1][kb], bk, sc[1][nf], 0, 0, 0);
      }
    }

    // scale + causal mask + online softmax
    for (int qf = 0; qf < 2; qf++) {
      for (int r = 0; r < 4; r++) {
        int qg = q0w + qf * 16 + kg * 4 + r;
        float rowmax = -__builtin_inff();
        for (int nf = 0; nf < 4; nf++) {
          float xv = sc[qf][nf][r] * 0.125f;
          int kvg = kv0 + nf * 16 + rl;
          xv = (kvg > qg) ? -__builtin_inff() : xv;
          sc[qf][nf][r] = xv;
          rowmax = fmaxf(rowmax, xv);
        }
        for (int msk = 1; msk < 16; msk <<= 1) rowmax = fmaxf(rowmax, __shfl_xor(rowmax, msk));
        float mnew = fmaxf(mrun[qf][r], rowmax);
        float corr = __expf(mrun[qf][r] - mnew);
        mrun[qf][r] = mnew;
        float rs = 0.f;
        for (int nf = 0; nf < 4; nf++) {
          float p = __expf(sc[qf][nf][r] - mnew);
          sc[qf][nf][r] = p;
          rs += p;
        }
        for (int msk = 1; msk < 16; msk <<= 1) rs += __shfl_xor(rs, msk);
        lrun[qf][r] = lrun[qf][r] * corr + rs;
        for (int nf = 0; nf < 4; nf++) o[qf][nf][r] *= corr;
      }
    }

    // write P (bf16, swizzled) to per-wave LDS scratch
    unsigned char* pbase = smem + 16384 + w * 4096;
    for (int qf = 0; qf < 2; qf++)
      for (int nf = 0; nf < 4; nf++)
        for (int r = 0; r < 4; r++) {
          int pr = qf * 16 + kg * 4 + r;
          int pc = nf * 16 + rl;
          *(bf16*)(pbase + ((pr * 128 + pc * 2) ^ ((pr & 7) << 4))) = (bf16)sc[qf][nf][r];
        }
    asm volatile("s_waitcnt lgkmcnt(0)" ::: "memory");

    // O += P V  (A=P from LDS, B=V^T rows from LDS)
    bf16x8 ap[2][2];
    for (int qf = 0; qf < 2; qf++)
      for (int kb = 0; kb < 2; kb++) {
        int prow = qf * 16 + rl;
        ap[qf][kb] = *(const bf16x8*)(pbase + ((prow * 128 + kb * 64 + kg * 16) ^ ((prow & 7) << 4)));
      }
    for (int nf = 0; nf < 4; nf++) {
      int c = nf * 16 + rl;
      for (int kb = 0; kb < 2; kb++) {
        bf16x8 bv = *(const bf16x8*)(smem + 8192 + ((c * 128 + kb * 64 + kg * 16) ^ ((c & 7) << 4)));
        o[0][nf] = __builtin_amdgcn_mfma_f32_16x16x32_bf16(ap[0][kb], bv, o[0][nf], 0, 0, 0);
        o[1][nf] = __builtin_amdgcn_mfma_f32_16x16x32_bf16(ap[1][kb], bv, o[1][nf], 0, 0, 0);
      }
    }
  }

  // epilogue: O normalized, write [B*S][D] bf16
  for (int qf = 0; qf < 2; qf++)
    for (int nf = 0; nf < 4; nf++)
      for (int r = 0; r < 4; r++) {
        int qg = q0w + qf * 16 + kg * 4 + r;
        int col = h * 64 + nf * 16 + rl;
        float v = o[qf][nf][r] / lrun[qf][r];
        O[((size_t)(b * 2048) + qg) * 1024 + col] = (bf16)v;
      }
}

extern "C" void kernel_launch(void* const* d_in, const int* in_sizes, int n_in,
                              void* d_out, int out_size, void* d_ws, size_t ws_size,
                              hipStream_t stream) {
  const float* x      = (const float*)d_in[0];
  const float* w_qkv  = (const float*)d_in[1];
  const float* w_proj = (const float*)d_in[2];
  const float* b_proj = (const float*)d_in[3];

  char* ws = (char*)d_ws;
  size_t off = 0;
  bf16* xb     = (bf16*)(ws + off); off += (size_t)M_ * D_ * 2;
  bf16* wqkvT  = (bf16*)(ws + off); off += (size_t)N3_ * D_ * 2;
  bf16* wprojT = (bf16*)(ws + off); off += (size_t)D_ * D_ * 2;
  bf16* qkvb   = (bf16*)(ws + off); off += (size_t)M_ * N3_ * 2;
  bf16* ob     = (bf16*)(ws + off); off += (size_t)M_ * D_ * 2;
  float* cosT  = (float*)(ws + off); off += (size_t)S_ * 32 * 4;
  float* sinT  = (float*)(ws + off); off += (size_t)S_ * 32 * 4;

  conv_f32_bf16<<<(M_ * D_ / 4 + 255) / 256, 256, 0, stream>>>(x, xb, M_ * D_ / 4);
  transpose_to_bf16<<<dim3(N3_ / 32, D_ / 32), dim3(32, 8), 0, stream>>>(w_qkv, wqkvT, D_, N3_);
  transpose_to_bf16<<<dim3(D_ / 32, D_ / 32), dim3(32, 8), 0, stream>>>(w_proj, wprojT, D_, D_);
  rope_table<<<(S_ * 32) / 256, 256, 0, stream>>>(cosT, sinT);
  gemm128<true><<<dim3(N3_ / 128, M_ / 128), 256, 0, stream>>>(xb, wqkvT, M_, N3_, D_, qkvb, nullptr, nullptr);
  rope_apply<<<(B_ * S_ * H_ * 32) / 256, 256, 0, stream>>>(qkvb, cosT, sinT);
  attn_kernel<<<dim3(B_ * H_, S_ / 128), 256, 0, stream>>>(qkvb, ob);
  gemm128<false><<<dim3(D_ / 128, M_ / 128), 256, 0, stream>>>(ob, wprojT, M_, D_, D_, nullptr, (float*)d_out, b_proj);
}

// Round 2
// 159.007 us; speedup vs baseline: 1.3237x; 1.3237x over previous
//
#include <hip/hip_runtime.h>
#include <stdint.h>
#include <math.h>

#define B_   2
#define S_   2048
#define D_   1024
#define H_   16
#define HD_  64
#define M_   (B_*S_)     // 4096
#define N3_  (3*D_)      // 3072

typedef __bf16 bf16;
typedef __bf16 bf16x2 __attribute__((ext_vector_type(2)));
typedef __bf16 bf16x4v __attribute__((ext_vector_type(4)));
typedef __bf16 bf16x8 __attribute__((ext_vector_type(8)));
typedef float  f32x4 __attribute__((ext_vector_type(4)));

__device__ __forceinline__ void gload_lds16(const void* g, void* l) {
  __builtin_amdgcn_global_load_lds(
      (__attribute__((address_space(1))) const unsigned int*)g,
      (__attribute__((address_space(3))) unsigned int*)l, 16, 0, 0);
}

// ---------------- convert x fp32 -> bf16 ----------------
__global__ __launch_bounds__(256) void conv_f32_bf16(const float* __restrict__ in,
                                                     bf16* __restrict__ out, int n4) {
  int i = blockIdx.x * 256 + threadIdx.x;
  if (i < n4) {
    float4 v = ((const float4*)in)[i];
    bf16x4v o;
    o[0] = (bf16)v.x; o[1] = (bf16)v.y; o[2] = (bf16)v.z; o[3] = (bf16)v.w;
    *(bf16x4v*)(out + (size_t)i * 4) = o;
  }
}

// ---------------- transpose fp32 [R][C] -> bf16 [C][R] ----------------
__global__ __launch_bounds__(256) void transpose_to_bf16(const float* __restrict__ in,
                                                         bf16* __restrict__ out, int R, int C) {
  __shared__ bf16 tile[32][33];
  int c0 = blockIdx.x * 32, r0 = blockIdx.y * 32;
  int tx = threadIdx.x, ty = threadIdx.y;   // 32 x 8
  for (int j = 0; j < 4; j++) {
    int r = r0 + ty + j * 8;
    tile[ty + j * 8][tx] = (bf16)in[(size_t)r * C + c0 + tx];
  }
  __syncthreads();
  for (int j = 0; j < 4; j++) {
    int c = c0 + ty + j * 8;
    out[(size_t)c * R + r0 + tx] = tile[tx][ty + j * 8];
  }
}

// ---------------- transpose V: qkv v-part [B*S][D] -> vt [(b*16+h)*64+d][S] ----------------
__global__ __launch_bounds__(256) void transpose_v(const bf16* __restrict__ qkv,
                                                   bf16* __restrict__ vt) {
  __shared__ bf16 tile[32][33];
  int s0 = blockIdx.x * 32;
  int c0 = blockIdx.y * 32;  // column index in [0, B*1024)
  int tx = threadIdx.x, ty = threadIdx.y;   // 32 x 8
  for (int j = 0; j < 4; j++) {
    int s = s0 + ty + j * 8;
    int c = c0 + tx;
    int b = c >> 10, hd = c & 1023;
    tile[ty + j * 8][tx] = qkv[((size_t)(b * 2048 + s)) * 3072 + 2048 + hd];
  }
  __syncthreads();
  for (int j = 0; j < 4; j++) {
    int c = c0 + ty + j * 8;
    int b = c >> 10, hd = c & 1023;
    vt[((size_t)(b * 1024 + hd)) * 2048 + s0 + tx] = tile[tx][ty + j * 8];
  }
}

// ---------------- RoPE table ----------------
__global__ __launch_bounds__(256) void rope_table(float* __restrict__ cosT, float* __restrict__ sinT) {
  int i = blockIdx.x * 256 + threadIdx.x;   // < 2048*32
  int s = i >> 5, d = i & 31;
  float inv = powf(10000.0f, -(float)d * (1.0f / 32.0f));
  float a = (float)s * inv;
  float sv, cv;
  sincosf(a, &sv, &cv);
  cosT[i] = cv; sinT[i] = sv;
}

// ---------------- RoPE apply (vectorized, in place on q,k parts) ----------------
__global__ __launch_bounds__(256) void rope_apply(bf16* __restrict__ qkv,
                                                  const float* __restrict__ cosT,
                                                  const float* __restrict__ sinT) {
  int i = blockIdx.x * 256 + threadIdx.x;   // < B*S*H*4 = 262144
  int d0 = (i & 3) * 8; int r = i >> 2;
  int h = r & 15; int s = (r >> 4) & 2047; int b = r >> 15;
  size_t base = ((size_t)(b * 2048 + s)) * 3072 + h * 64;
  float4 c0 = *(const float4*)(cosT + s * 32 + d0);
  float4 c1 = *(const float4*)(cosT + s * 32 + d0 + 4);
  float4 s0 = *(const float4*)(sinT + s * 32 + d0);
  float4 s1 = *(const float4*)(sinT + s * 32 + d0 + 4);
  float cc[8] = {c0.x, c0.y, c0.z, c0.w, c1.x, c1.y, c1.z, c1.w};
  float ss[8] = {s0.x, s0.y, s0.z, s0.w, s1.x, s1.y, s1.z, s1.w};
#pragma unroll
  for (int part = 0; part < 2; part++) {
    size_t p = base + part * 1024;
    bf16x8 x1 = *(bf16x8*)(qkv + p + d0);
    bf16x8 x2 = *(bf16x8*)(qkv + p + d0 + 32);
    bf16x8 o1, o2;
#pragma unroll
    for (int e = 0; e < 8; e++) {
      float a = (float)x1[e], b2 = (float)x2[e];
      o1[e] = (bf16)(a * cc[e] - b2 * ss[e]);
      o2[e] = (bf16)(b2 * cc[e] + a * ss[e]);
    }
    *(bf16x8*)(qkv + p + d0) = o1;
    *(bf16x8*)(qkv + p + d0 + 32) = o2;
  }
}

// ---------------- GEMM: C[M][N] = A[M][K] * Bt[N][K]^T ----------------
template<bool OUT_BF16>
__global__ __launch_bounds__(256) void gemm128(const bf16* __restrict__ A,
                                               const bf16* __restrict__ Bt,
                                               int M, int N, int K,
                                               bf16* __restrict__ Cb,
                                               float* __restrict__ Cf,
                                               const float* __restrict__ bias) {
  __shared__ bf16 As[128 * 32];
  __shared__ bf16 Bs[128 * 32];
  int tid = threadIdx.x;
  int lane = tid & 63, w = tid >> 6;
  int m0 = blockIdx.y * 128, n0 = blockIdx.x * 128;
  int m_off = (w >> 1) * 64, n_off = (w & 1) * 64;
  f32x4 acc[4][4] = {};

  const char* Ab = (const char*)A;
  const char* Bb = (const char*)Bt;
  int srow = (lane >> 2);
  int skb  = (lane & 3) * 16;

  for (int k0 = 0; k0 < K; k0 += 32) {
    for (int j = 0; j < 2; j++) {
      int seg = j * 4 + w;
      int row = seg * 16 + srow;
      gload_lds16(Ab + ((size_t)(m0 + row) * K + k0) * 2 + skb, (char*)As + seg * 1024);
      gload_lds16(Bb + ((size_t)(n0 + row) * K + k0) * 2 + skb, (char*)Bs + seg * 1024);
    }
    __syncthreads();
    int rl = lane & 15;
    int kgb = (lane >> 4) * 16;
    bf16x8 a[4], b[4];
    for (int i = 0; i < 4; i++)
      a[i] = *(const bf16x8*)((const char*)As + (m_off + i * 16 + rl) * 64 + kgb);
    for (int i = 0; i < 4; i++)
      b[i] = *(const bf16x8*)((const char*)Bs + (n_off + i * 16 + rl) * 64 + kgb);
    for (int i = 0; i < 4; i++)
      for (int j = 0; j < 4; j++)
        acc[i][j] = __builtin_amdgcn_mfma_f32_16x16x32_bf16(a[i], b[j], acc[i][j], 0, 0, 0);
    __syncthreads();
  }

  int rq = (lane >> 4) * 4, cl = lane & 15;
  for (int i = 0; i < 4; i++)
    for (int j = 0; j < 4; j++) {
      int col = n0 + n_off + j * 16 + cl;
      for (int r = 0; r < 4; r++) {
        int row = m0 + m_off + i * 16 + rq + r;
        float v = acc[i][j][r];
        if constexpr (OUT_BF16) Cb[(size_t)row * N + col] = (bf16)v;
        else                    Cf[(size_t)row * N + col] = v + bias[col];
      }
    }
}

// ---------------- flash attention (swapped QK^T, in-register softmax) ----------------
// grid: 512 blocks; 256 threads (4 waves); wave w owns 32 q-rows of a 128-row q-tile.
__global__ __launch_bounds__(256) void attn_kernel(const bf16* __restrict__ qkv,
                                                   const bf16* __restrict__ vt,
                                                   bf16* __restrict__ O) {
  __shared__ __align__(16) unsigned char Ks[8192];
  __shared__ __align__(16) unsigned char Vs[8192];
  int tid = threadIdx.x, lane = tid & 63, w = tid >> 6;
  int bid = blockIdx.x;
  int xcd = bid & 7, slot = bid >> 3;
  int bh = xcd * 4 + (slot & 3);          // 4 heads per XCD -> KV L2-resident
  int qt = 15 - (slot >> 2);              // heavy q-tiles dispatched first
  int b = bh >> 4, h = bh & 15;
  int q0w = qt * 128 + w * 32;
  int rl = lane & 15, G = lane >> 4;
  const char* qb = (const char*)qkv;
  const char* vb = (const char*)vt;

  // Q fragments (B-operand rows), scale folded in (exact in bf16)
  bf16x8 aq[2][2];
#pragma unroll
  for (int qf = 0; qf < 2; qf++)
#pragma unroll
    for (int kb = 0; kb < 2; kb++) {
      size_t row = (size_t)(b * 2048 + q0w + qf * 16 + rl);
      bf16x8 v = *(const bf16x8*)(qb + (row * 3072 + h * 64 + kb * 32 + G * 8) * 2);
#pragma unroll
      for (int e = 0; e < 8; e++) v[e] = (bf16)((float)v[e] * 0.125f);
      aq[qf][kb] = v;
    }

  f32x4 o[2][4] = {};
  float mrun[2] = {-3e38f, -3e38f}, lrun[2] = {0.f, 0.f};

  int srow = lane >> 3;              // row within 8-row seg
  int schunk = (lane & 7) ^ srow;    // pre-swizzled 16B chunk (involution)
  int ntiles = 2 * qt + 2;

  for (int t = 0; t < ntiles; t++) {
    int kv0 = t * 64;
    __syncthreads();
#pragma unroll
    for (int rep = 0; rep < 2; rep++) {
      int seg = w + rep * 4;
      int row = seg * 8 + srow;
      gload_lds16(qb + (((size_t)(b * 2048 + kv0 + row) * 3072) + 1024 + h * 64) * 2 + schunk * 16,
                  (char*)Ks + seg * 1024);
      gload_lds16(vb + (((size_t)(bh * 64 + row) * 2048) + kv0) * 2 + schunk * 16,
                  (char*)Vs + seg * 1024);
    }
    __syncthreads();
    if (kv0 > q0w + 31) continue;          // tile fully masked for this wave
    bool diag = (kv0 + 63 > q0w);          // needs causal masking

    // S^T = K * Q^T : C[k][q], lane col = q, rows = k in regs
    f32x4 sc[4][2];
#pragma unroll
    for (int kf = 0; kf < 4; kf++)
#pragma unroll
      for (int qf = 0; qf < 2; qf++) { sc[kf][qf][0] = 0.f; sc[kf][qf][1] = 0.f; sc[kf][qf][2] = 0.f; sc[kf][qf][3] = 0.f; }
#pragma unroll
    for (int kb = 0; kb < 2; kb++) {
      bf16x8 ak[4];
#pragma unroll
      for (int kf = 0; kf < 4; kf++) {
        int row = kf * 16 + rl;
        int ch = (kb * 4 + G) ^ (row & 7);
        ak[kf] = *(const bf16x8*)(Ks + row * 128 + ch * 16);
      }
#pragma unroll
      for (int kf = 0; kf < 4; kf++)
#pragma unroll
        for (int qf = 0; qf < 2; qf++)
          sc[kf][qf] = __builtin_amdgcn_mfma_f32_16x16x32_bf16(ak[kf], aq[qf][kb], sc[kf][qf], 0, 0, 0);
    }

    // online softmax per q-column (lane-local row, 2 shfl per reduce)
    unsigned pk[4][2][2];
#pragma unroll
    for (int qf = 0; qf < 2; qf++) {
      int qcol = q0w + qf * 16 + rl;
      if (diag) {
#pragma unroll
        for (int kf = 0; kf < 4; kf++)
#pragma unroll
          for (int r = 0; r < 4; r++) {
            int k = kv0 + kf * 16 + G * 4 + r;
            if (k > qcol) sc[kf][qf][r] = -3e38f;
          }
      }
      float mx = -3e38f;
#pragma unroll
      for (int kf = 0; kf < 4; kf++)
#pragma unroll
        for (int r = 0; r < 4; r++) mx = fmaxf(mx, sc[kf][qf][r]);
      mx = fmaxf(mx, __shfl_xor(mx, 16));
      mx = fmaxf(mx, __shfl_xor(mx, 32));
      float mnew = fmaxf(mrun[qf], mx);
      float corr = __expf(mrun[qf] - mnew);
      mrun[qf] = mnew;
      float rs = 0.f;
#pragma unroll
      for (int kf = 0; kf < 4; kf++)
#pragma unroll
        for (int r = 0; r < 4; r++) {
          float p = __expf(sc[kf][qf][r] - mnew);
          sc[kf][qf][r] = p;
          rs += p;
        }
      rs += __shfl_xor(rs, 16);
      rs += __shfl_xor(rs, 32);
      lrun[qf] = lrun[qf] * corr + rs;
#pragma unroll
      for (int r = 0; r < 4; r++) {
        float cr = __shfl(corr, G * 4 + r);
#pragma unroll
        for (int nf = 0; nf < 4; nf++) o[qf][nf][r] *= cr;
      }
      // pack P pairs (k even/odd) to bf16x2 dwords
#pragma unroll
      for (int kf = 0; kf < 4; kf++)
#pragma unroll
        for (int pr = 0; pr < 2; pr++) {
          bf16x2 tp;
          tp[0] = (bf16)sc[kf][qf][2 * pr];
          tp[1] = (bf16)sc[kf][qf][2 * pr + 1];
          pk[kf][qf][pr] = __builtin_bit_cast(unsigned, tp);
        }
    }

    // redistribute P^T (lane=q-col, k in regs) -> P A-fragments (lane=q-row, k contiguous)
#pragma unroll
    for (int kb = 0; kb < 2; kb++) {
      bf16x8 ap[2];
#pragma unroll
      for (int qf = 0; qf < 2; qf++) {
        union { unsigned u[4]; bf16x8 v; } cvt;
#pragma unroll
        for (int d = 0; d < 4; d++) {
          int src = ((G & 1) * 2 + (d >> 1)) * 16 + rl;
          unsigned lo = __shfl(pk[kb * 2][qf][d & 1], src);
          unsigned hi = __shfl(pk[kb * 2 + 1][qf][d & 1], src);
          cvt.u[d] = (G >> 1) ? hi : lo;
        }
        ap[qf] = cvt.v;
      }
#pragma unroll
      for (int nf = 0; nf < 4; nf++) {
        int row = nf * 16 + rl;
        int ch = (kb * 4 + G) ^ (row & 7);
        bf16x8 bv = *(const bf16x8*)(Vs + row * 128 + ch * 16);
#pragma unroll
        for (int qf = 0; qf < 2; qf++)
          o[qf][nf] = __builtin_amdgcn_mfma_f32_16x16x32_bf16(ap[qf], bv, o[qf][nf], 0, 0, 0);
      }
    }
  }

  // epilogue
#pragma unroll
  for (int qf = 0; qf < 2; qf++) {
    float linv = 1.0f / lrun[qf];
#pragma unroll
    for (int r = 0; r < 4; r++) {
      float lr = __shfl(linv, G * 4 + r);
      int row = b * 2048 + q0w + qf * 16 + G * 4 + r;
#pragma unroll
      for (int nf = 0; nf < 4; nf++)
        O[(size_t)row * 1024 + h * 64 + nf * 16 + rl] = (bf16)(o[qf][nf][r] * lr);
    }
  }
}

extern "C" void kernel_launch(void* const* d_in, const int* in_sizes, int n_in,
                              void* d_out, int out_size, void* d_ws, size_t ws_size,
                              hipStream_t stream) {
  const float* x      = (const float*)d_in[0];
  const float* w_qkv  = (const float*)d_in[1];
  const float* w_proj = (const float*)d_in[2];
  const float* b_proj = (const float*)d_in[3];

  char* ws = (char*)d_ws;
  size_t off = 0;
  bf16* xb     = (bf16*)(ws + off); off += (size_t)M_ * D_ * 2;
  bf16* wqkvT  = (bf16*)(ws + off); off += (size_t)N3_ * D_ * 2;
  bf16* wprojT = (bf16*)(ws + off); off += (size_t)D_ * D_ * 2;
  bf16* qkvb   = (bf16*)(ws + off); off += (size_t)M_ * N3_ * 2;
  bf16* ob     = (bf16*)(ws + off); off += (size_t)M_ * D_ * 2;
  bf16* vtb    = (bf16*)(ws + off); off += (size_t)M_ * D_ * 2;
  float* cosT  = (float*)(ws + off); off += (size_t)S_ * 32 * 4;
  float* sinT  = (float*)(ws + off); off += (size_t)S_ * 32 * 4;

  conv_f32_bf16<<<(M_ * D_ / 4 + 255) / 256, 256, 0, stream>>>(x, xb, M_ * D_ / 4);
  transpose_to_bf16<<<dim3(N3_ / 32, D_ / 32), dim3(32, 8), 0, stream>>>(w_qkv, wqkvT, D_, N3_);
  transpose_to_bf16<<<dim3(D_ / 32, D_ / 32), dim3(32, 8), 0, stream>>>(w_proj, wprojT, D_, D_);
  rope_table<<<(S_ * 32) / 256, 256, 0, stream>>>(cosT, sinT);
  gemm128<true><<<dim3(N3_ / 128, M_ / 128), 256, 0, stream>>>(xb, wqkvT, M_, N3_, D_, qkvb, nullptr, nullptr);
  rope_apply<<<(B_ * S_ * H_ * 4) / 256, 256, 0, stream>>>(qkvb, cosT, sinT);
  transpose_v<<<dim3(S_ / 32, B_ * D_ / 32), dim3(32, 8), 0, stream>>>(qkvb, vtb);
  attn_kernel<<<512, 256, 0, stream>>>(qkvb, vtb, ob);
  gemm128<false><<<dim3(D_ / 128, M_ / 128), 256, 0, stream>>>(ob, wprojT, M_, D_, D_, nullptr, (float*)d_out, b_proj);
}

// Round 3
// 146.274 us; speedup vs baseline: 1.4389x; 1.0870x over previous
//
#include <hip/hip_runtime.h>
#include <stdint.h>
#include <math.h>

#define B_   2
#define S_   2048
#define D_   1024
#define H_   16
#define HD_  64
#define M_   (B_*S_)     // 4096
#define N3_  (3*D_)      // 3072

typedef __bf16 bf16;
typedef __bf16 bf16x2 __attribute__((ext_vector_type(2)));
typedef __bf16 bf16x4v __attribute__((ext_vector_type(4)));
typedef __bf16 bf16x8 __attribute__((ext_vector_type(8)));
typedef float  f32x4 __attribute__((ext_vector_type(4)));

__device__ __forceinline__ void gload_lds16(const void* g, void* l) {
  __builtin_amdgcn_global_load_lds(
      (__attribute__((address_space(1))) const unsigned int*)g,
      (__attribute__((address_space(3))) unsigned int*)l, 16, 0, 0);
}

// ---------------- convert x fp32 -> bf16 ----------------
__global__ __launch_bounds__(256) void conv_f32_bf16(const float* __restrict__ in,
                                                     bf16* __restrict__ out, int n4) {
  int i = blockIdx.x * 256 + threadIdx.x;
  if (i < n4) {
    float4 v = ((const float4*)in)[i];
    bf16x4v o;
    o[0] = (bf16)v.x; o[1] = (bf16)v.y; o[2] = (bf16)v.z; o[3] = (bf16)v.w;
    *(bf16x4v*)(out + (size_t)i * 4) = o;
  }
}

// ---------------- transpose fp32 [R][C] -> bf16 [C][R] ----------------
__global__ __launch_bounds__(256) void transpose_to_bf16(const float* __restrict__ in,
                                                         bf16* __restrict__ out, int R, int C) {
  __shared__ bf16 tile[32][33];
  int c0 = blockIdx.x * 32, r0 = blockIdx.y * 32;
  int tx = threadIdx.x, ty = threadIdx.y;   // 32 x 8
  for (int j = 0; j < 4; j++) {
    int r = r0 + ty + j * 8;
    tile[ty + j * 8][tx] = (bf16)in[(size_t)r * C + c0 + tx];
  }
  __syncthreads();
  for (int j = 0; j < 4; j++) {
    int c = c0 + ty + j * 8;
    out[(size_t)c * R + r0 + tx] = tile[tx][ty + j * 8];
  }
}

// ---------------- transpose V: qkv v-part [B*S][D] -> vt [(b*16+h)*64+d][S] ----------------
__global__ __launch_bounds__(256) void transpose_v(const bf16* __restrict__ qkv,
                                                   bf16* __restrict__ vt) {
  __shared__ bf16 tile[32][33];
  int s0 = blockIdx.x * 32;
  int c0 = blockIdx.y * 32;
  int tx = threadIdx.x, ty = threadIdx.y;
  for (int j = 0; j < 4; j++) {
    int s = s0 + ty + j * 8;
    int c = c0 + tx;
    int b = c >> 10, hd = c & 1023;
    tile[ty + j * 8][tx] = qkv[((size_t)(b * 2048 + s)) * 3072 + 2048 + hd];
  }
  __syncthreads();
  for (int j = 0; j < 4; j++) {
    int c = c0 + ty + j * 8;
    int b = c >> 10, hd = c & 1023;
    vt[((size_t)(b * 1024 + hd)) * 2048 + s0 + tx] = tile[tx][ty + j * 8];
  }
}

// ---------------- RoPE table ----------------
__global__ __launch_bounds__(256) void rope_table(float* __restrict__ cosT, float* __restrict__ sinT) {
  int i = blockIdx.x * 256 + threadIdx.x;   // < 2048*32
  int s = i >> 5, d = i & 31;
  float inv = powf(10000.0f, -(float)d * (1.0f / 32.0f));
  float a = (float)s * inv;
  float sv, cv;
  sincosf(a, &sv, &cv);
  cosT[i] = cv; sinT[i] = sv;
}

// ---------------- GEMM: C[M][N] = A[M][K] * Bt[N][K]^T ----------------
// OUT_BF16 path fuses RoPE (cols < 2048 are q/k; pairs (d, d+32) = acc cols (j, j+2)).
template<bool OUT_BF16>
__global__ __launch_bounds__(256) void gemm128(const bf16* __restrict__ A,
                                               const bf16* __restrict__ Bt,
                                               int M, int N, int K,
                                               bf16* __restrict__ Cb,
                                               float* __restrict__ Cf,
                                               const float* __restrict__ bias,
                                               const float* __restrict__ cosT,
                                               const float* __restrict__ sinT) {
  __shared__ bf16 As[128 * 32];
  __shared__ bf16 Bs[128 * 32];
  int tid = threadIdx.x;
  int lane = tid & 63, w = tid >> 6;
  // XCD-aware swizzle (nwg % 8 == 0 for all our grids)
  int nwg = gridDim.x * gridDim.y;
  int bid = blockIdx.y * gridDim.x + blockIdx.x;
  int sw = (bid & 7) * (nwg >> 3) + (bid >> 3);
  int bx = sw % gridDim.x, by = sw / gridDim.x;
  int m0 = by * 128, n0 = bx * 128;
  int m_off = (w >> 1) * 64, n_off = (w & 1) * 64;
  f32x4 acc[4][4] = {};

  const char* Ab = (const char*)A;
  const char* Bb = (const char*)Bt;
  int srow = (lane >> 2);
  int skb  = (lane & 3) * 16;

  for (int k0 = 0; k0 < K; k0 += 32) {
    for (int j = 0; j < 2; j++) {
      int seg = j * 4 + w;
      int row = seg * 16 + srow;
      gload_lds16(Ab + ((size_t)(m0 + row) * K + k0) * 2 + skb, (char*)As + seg * 1024);
      gload_lds16(Bb + ((size_t)(n0 + row) * K + k0) * 2 + skb, (char*)Bs + seg * 1024);
    }
    __syncthreads();
    int rl = lane & 15;
    int kgb = (lane >> 4) * 16;
    bf16x8 a[4], b[4];
    for (int i = 0; i < 4; i++)
      a[i] = *(const bf16x8*)((const char*)As + (m_off + i * 16 + rl) * 64 + kgb);
    for (int i = 0; i < 4; i++)
      b[i] = *(const bf16x8*)((const char*)Bs + (n_off + i * 16 + rl) * 64 + kgb);
    for (int i = 0; i < 4; i++)
      for (int j = 0; j < 4; j++)
        acc[i][j] = __builtin_amdgcn_mfma_f32_16x16x32_bf16(a[i], b[j], acc[i][j], 0, 0, 0);
    __syncthreads();
  }

  int rq = (lane >> 4) * 4, cl = lane & 15;
  if constexpr (OUT_BF16) {
    bool rope = (n0 + n_off) < 2048;   // q/k region (64-col span is head-aligned)
    for (int i = 0; i < 4; i++)
      for (int r = 0; r < 4; r++) {
        int row = m0 + m_off + i * 16 + rq + r;
        int srw = row & 2047;
        if (rope) {
          for (int j = 0; j < 2; j++) {
            int d2 = j * 16 + cl;
            float c = cosT[srw * 32 + d2], sn = sinT[srw * 32 + d2];
            float x1 = acc[i][j][r], x2 = acc[i][j + 2][r];
            Cb[(size_t)row * N + n0 + n_off + d2]      = (bf16)(x1 * c - x2 * sn);
            Cb[(size_t)row * N + n0 + n_off + d2 + 32] = (bf16)(x2 * c + x1 * sn);
          }
        } else {
          for (int j = 0; j < 4; j++)
            Cb[(size_t)row * N + n0 + n_off + j * 16 + cl] = (bf16)acc[i][j][r];
        }
      }
  } else {
    for (int i = 0; i < 4; i++)
      for (int j = 0; j < 4; j++) {
        int col = n0 + n_off + j * 16 + cl;
        for (int r = 0; r < 4; r++) {
          int row = m0 + m_off + i * 16 + rq + r;
          Cf[(size_t)row * N + col] = acc[i][j][r] + bias[col];
        }
      }
  }
}

// ---------------- flash attention (8 waves, dbuf staging, swapped QK^T) ----------------
// grid: 512 blocks x 512 threads; wave w owns 16 q-rows of a 128-row q-tile.
__global__ __launch_bounds__(512) void attn_kernel(const bf16* __restrict__ qkv,
                                                   const bf16* __restrict__ vt,
                                                   bf16* __restrict__ O) {
  __shared__ __align__(16) unsigned char Ks[2][8192];
  __shared__ __align__(16) unsigned char Vs[2][8192];
  int tid = threadIdx.x, lane = tid & 63, w = tid >> 6;   // w: 0..7
  int bid = blockIdx.x;
  int xcd = bid & 7, slot = bid >> 3;
  int bh = xcd * 4 + (slot & 3);          // 4 heads per XCD
  int u = slot >> 2;                       // 0..15
  int qt = (u < 8) ? (15 - u) : (u - 8);  // blocks bid, bid+256 pair to qt sum 15
  int b = bh >> 4, h = bh & 15;
  int q0w = qt * 128 + w * 16;
  int rl = lane & 15, G = lane >> 4;
  const char* qb = (const char*)qkv;
  const char* vb = (const char*)vt;

  // Q fragments (B-operand rows), 1/8 scale folded in (exact in bf16)
  bf16x8 aq[2];
#pragma unroll
  for (int kb = 0; kb < 2; kb++) {
    size_t row = (size_t)(b * 2048 + q0w + rl);
    bf16x8 v = *(const bf16x8*)(qb + (row * 3072 + h * 64 + kb * 32 + G * 8) * 2);
#pragma unroll
    for (int e = 0; e < 8; e++) v[e] = (bf16)((float)v[e] * 0.125f);
    aq[kb] = v;
  }

  f32x4 o[4] = {};
  float mrun = -3e38f, lrun = 0.f;

  int srow = lane >> 3;              // row within this wave's 8-row seg
  int schunk = (lane & 7) ^ srow;    // pre-swizzled 16B chunk (involution)
  int ntiles = 2 * qt + 2;

  // prologue: stage tile 0 into buf 0
  {
    int row = w * 8 + srow;
    gload_lds16(qb + (((size_t)(b * 2048 + row) * 3072) + 1024 + h * 64) * 2 + schunk * 16,
                (char*)Ks[0] + w * 1024);
    gload_lds16(vb + (((size_t)(bh * 64 + row) * 2048)) * 2 + schunk * 16,
                (char*)Vs[0] + w * 1024);
  }
  asm volatile("s_waitcnt vmcnt(0)" ::: "memory");
  __builtin_amdgcn_s_barrier();

  for (int t = 0; t < ntiles; t++) {
    int kv0 = t * 64;
    int cur = t & 1;
    // issue next tile's staging loads (hidden under this tile's compute)
    if (t + 1 < ntiles) {
      int kvn = kv0 + 64;
      int row = w * 8 + srow;
      gload_lds16(qb + (((size_t)(b * 2048 + kvn + row) * 3072) + 1024 + h * 64) * 2 + schunk * 16,
                  (char*)Ks[cur ^ 1] + w * 1024);
      gload_lds16(vb + (((size_t)(bh * 64 + row) * 2048) + kvn) * 2 + schunk * 16,
                  (char*)Vs[cur ^ 1] + w * 1024);
    }

    if (kv0 <= q0w + 15) {
      bool diag = (kv0 + 63 > q0w);

      // S^T = K * Q^T : C[k][q], lane col = q
      f32x4 sc[4];
#pragma unroll
      for (int kf = 0; kf < 4; kf++) { sc[kf][0] = 0.f; sc[kf][1] = 0.f; sc[kf][2] = 0.f; sc[kf][3] = 0.f; }
#pragma unroll
      for (int kb = 0; kb < 2; kb++) {
#pragma unroll
        for (int kf = 0; kf < 4; kf++) {
          int row = kf * 16 + rl;
          int ch = (kb * 4 + G) ^ (row & 7);
          bf16x8 ak = *(const bf16x8*)(Ks[cur] + row * 128 + ch * 16);
          sc[kf] = __builtin_amdgcn_mfma_f32_16x16x32_bf16(ak, aq[kb], sc[kf], 0, 0, 0);
        }
      }

      // online softmax per q-column (lane-local, 2 shfl per reduce)
      int qcol = q0w + rl;
      if (diag) {
#pragma unroll
        for (int kf = 0; kf < 4; kf++)
#pragma unroll
          for (int r = 0; r < 4; r++) {
            int k = kv0 + kf * 16 + G * 4 + r;
            if (k > qcol) sc[kf][r] = -3e38f;
          }
      }
      float mx = -3e38f;
#pragma unroll
      for (int kf = 0; kf < 4; kf++)
#pragma unroll
        for (int r = 0; r < 4; r++) mx = fmaxf(mx, sc[kf][r]);
      mx = fmaxf(mx, __shfl_xor(mx, 16));
      mx = fmaxf(mx, __shfl_xor(mx, 32));
      float mnew = fmaxf(mrun, mx);
      float corr = __expf(mrun - mnew);
      mrun = mnew;
      float rs = 0.f;
#pragma unroll
      for (int kf = 0; kf < 4; kf++)
#pragma unroll
        for (int r = 0; r < 4; r++) {
          float p = __expf(sc[kf][r] - mnew);
          sc[kf][r] = p;
          rs += p;
        }
      rs += __shfl_xor(rs, 16);
      rs += __shfl_xor(rs, 32);
      lrun = lrun * corr + rs;
#pragma unroll
      for (int r = 0; r < 4; r++) {
        float cr = __shfl(corr, G * 4 + r);
#pragma unroll
        for (int nf = 0; nf < 4; nf++) o[nf][r] *= cr;
      }
      // pack P pairs to bf16x2 dwords
      unsigned pk[4][2];
#pragma unroll
      for (int kf = 0; kf < 4; kf++)
#pragma unroll
        for (int pr = 0; pr < 2; pr++) {
          bf16x2 tp;
          tp[0] = (bf16)sc[kf][2 * pr];
          tp[1] = (bf16)sc[kf][2 * pr + 1];
          pk[kf][pr] = __builtin_bit_cast(unsigned, tp);
        }

      // redistribute P^T -> P A-fragments; PV
#pragma unroll
      for (int kb = 0; kb < 2; kb++) {
        union { unsigned u[4]; bf16x8 v; } cvt;
#pragma unroll
        for (int d = 0; d < 4; d++) {
          int src = ((G & 1) * 2 + (d >> 1)) * 16 + rl;
          unsigned lo = __shfl(pk[kb * 2][d & 1], src);
          unsigned hi = __shfl(pk[kb * 2 + 1][d & 1], src);
          cvt.u[d] = (G >> 1) ? hi : lo;
        }
        bf16x8 ap = cvt.v;
#pragma unroll
        for (int nf = 0; nf < 4; nf++) {
          int row = nf * 16 + rl;
          int ch = (kb * 4 + G) ^ (row & 7);
          bf16x8 bv = *(const bf16x8*)(Vs[cur] + row * 128 + ch * 16);
          o[nf] = __builtin_amdgcn_mfma_f32_16x16x32_bf16(ap, bv, o[nf], 0, 0, 0);
        }
      }
    }

    asm volatile("s_waitcnt vmcnt(0)" ::: "memory");
    __builtin_amdgcn_s_barrier();
  }

  // epilogue
  float linv = 1.0f / lrun;
#pragma unroll
  for (int r = 0; r < 4; r++) {
    float lr = __shfl(linv, G * 4 + r);
    int row = b * 2048 + q0w + G * 4 + r;
#pragma unroll
    for (int nf = 0; nf < 4; nf++)
      O[(size_t)row * 1024 + h * 64 + nf * 16 + rl] = (bf16)(o[nf][r] * lr);
  }
}

extern "C" void kernel_launch(void* const* d_in, const int* in_sizes, int n_in,
                              void* d_out, int out_size, void* d_ws, size_t ws_size,
                              hipStream_t stream) {
  const float* x      = (const float*)d_in[0];
  const float* w_qkv  = (const float*)d_in[1];
  const float* w_proj = (const float*)d_in[2];
  const float* b_proj = (const float*)d_in[3];

  char* ws = (char*)d_ws;
  size_t off = 0;
  bf16* xb     = (bf16*)(ws + off); off += (size_t)M_ * D_ * 2;
  bf16* wqkvT  = (bf16*)(ws + off); off += (size_t)N3_ * D_ * 2;
  bf16* wprojT = (bf16*)(ws + off); off += (size_t)D_ * D_ * 2;
  bf16* qkvb   = (bf16*)(ws + off); off += (size_t)M_ * N3_ * 2;
  bf16* ob     = (bf16*)(ws + off); off += (size_t)M_ * D_ * 2;
  bf16* vtb    = (bf16*)(ws + off); off += (size_t)M_ * D_ * 2;
  float* cosT  = (float*)(ws + off); off += (size_t)S_ * 32 * 4;
  float* sinT  = (float*)(ws + off); off += (size_t)S_ * 32 * 4;

  conv_f32_bf16<<<(M_ * D_ / 4 + 255) / 256, 256, 0, stream>>>(x, xb, M_ * D_ / 4);
  transpose_to_bf16<<<dim3(N3_ / 32, D_ / 32), dim3(32, 8), 0, stream>>>(w_qkv, wqkvT, D_, N3_);
  transpose_to_bf16<<<dim3(D_ / 32, D_ / 32), dim3(32, 8), 0, stream>>>(w_proj, wprojT, D_, D_);
  rope_table<<<(S_ * 32) / 256, 256, 0, stream>>>(cosT, sinT);
  gemm128<true><<<dim3(N3_ / 128, M_ / 128), 256, 0, stream>>>(xb, wqkvT, M_, N3_, D_, qkvb, nullptr, nullptr, cosT, sinT);
  transpose_v<<<dim3(S_ / 32, B_ * D_ / 32), dim3(32, 8), 0, stream>>>(qkvb, vtb);
  attn_kernel<<<512, 512, 0, stream>>>(qkvb, vtb, ob);
  gemm128<false><<<dim3(D_ / 128, M_ / 128), 256, 0, stream>>>(ob, wprojT, M_, D_, D_, nullptr, (float*)d_out, b_proj, nullptr, nullptr);
}

// Round 6
// 142.893 us; speedup vs baseline: 1.4730x; 1.0237x over previous
//
#include <hip/hip_runtime.h>
#include <stdint.h>
#include <math.h>

#define B_   2
#define S_   2048
#define D_   1024
#define H_   16
#define HD_  64
#define M_   (B_*S_)     // 4096
#define N3_  (3*D_)      // 3072

typedef __bf16 bf16;
typedef __bf16 bf16x2 __attribute__((ext_vector_type(2)));
typedef __bf16 bf16x4v __attribute__((ext_vector_type(4)));
typedef __bf16 bf16x8 __attribute__((ext_vector_type(8)));
typedef float  f32x4 __attribute__((ext_vector_type(4)));
typedef float  f32x16 __attribute__((ext_vector_type(16)));

__device__ __forceinline__ void gload_lds16(const void* g, void* l) {
  __builtin_amdgcn_global_load_lds(
      (__attribute__((address_space(1))) const unsigned int*)g,
      (__attribute__((address_space(3))) unsigned int*)l, 16, 0, 0);
}

// ---------------- convert x fp32 -> bf16 ----------------
__global__ __launch_bounds__(256) void conv_f32_bf16(const float* __restrict__ in,
                                                     bf16* __restrict__ out, int n4) {
  int i = blockIdx.x * 256 + threadIdx.x;
  if (i < n4) {
    float4 v = ((const float4*)in)[i];
    bf16x4v o;
    o[0] = (bf16)v.x; o[1] = (bf16)v.y; o[2] = (bf16)v.z; o[3] = (bf16)v.w;
    *(bf16x4v*)(out + (size_t)i * 4) = o;
  }
}

// ---------------- transpose fp32 [R][C] -> bf16 [C][R] ----------------
__global__ __launch_bounds__(256) void transpose_to_bf16(const float* __restrict__ in,
                                                         bf16* __restrict__ out, int R, int C) {
  __shared__ bf16 tile[32][33];
  int c0 = blockIdx.x * 32, r0 = blockIdx.y * 32;
  int tx = threadIdx.x, ty = threadIdx.y;   // 32 x 8
  for (int j = 0; j < 4; j++) {
    int r = r0 + ty + j * 8;
    tile[ty + j * 8][tx] = (bf16)in[(size_t)r * C + c0 + tx];
  }
  __syncthreads();
  for (int j = 0; j < 4; j++) {
    int c = c0 + ty + j * 8;
    out[(size_t)c * R + r0 + tx] = tile[tx][ty + j * 8];
  }
}

// ---------------- transpose V: qkv v-part [B*S][D] -> vt [(b*16+h)*64+d][S] ----------------
__global__ __launch_bounds__(256) void transpose_v(const bf16* __restrict__ qkv,
                                                   bf16* __restrict__ vt) {
  __shared__ bf16 tile[32][33];
  int s0 = blockIdx.x * 32;
  int c0 = blockIdx.y * 32;
  int tx = threadIdx.x, ty = threadIdx.y;
  for (int j = 0; j < 4; j++) {
    int s = s0 + ty + j * 8;
    int c = c0 + tx;
    int b = c >> 10, hd = c & 1023;
    tile[ty + j * 8][tx] = qkv[((size_t)(b * 2048 + s)) * 3072 + 2048 + hd];
  }
  __syncthreads();
  for (int j = 0; j < 4; j++) {
    int c = c0 + ty + j * 8;
    int b = c >> 10, hd = c & 1023;
    vt[((size_t)(b * 1024 + hd)) * 2048 + s0 + tx] = tile[tx][ty + j * 8];
  }
}

// ---------------- RoPE table ----------------
__global__ __launch_bounds__(256) void rope_table(float* __restrict__ cosT, float* __restrict__ sinT) {
  int i = blockIdx.x * 256 + threadIdx.x;   // < 2048*32
  int s = i >> 5, d = i & 31;
  float inv = powf(10000.0f, -(float)d * (1.0f / 32.0f));
  float a = (float)s * inv;
  float sv, cv;
  sincosf(a, &sv, &cv);
  cosT[i] = cv; sinT[i] = sv;
}

// ---------------- GEMM: C[M][N] = A[M][K] * Bt[N][K]^T ----------------
template<bool OUT_BF16>
__global__ __launch_bounds__(256) void gemm128(const bf16* __restrict__ A,
                                               const bf16* __restrict__ Bt,
                                               int M, int N, int K,
                                               bf16* __restrict__ Cb,
                                               float* __restrict__ Cf,
                                               const float* __restrict__ bias,
                                               const float* __restrict__ cosT,
                                               const float* __restrict__ sinT) {
  __shared__ bf16 As[128 * 32];
  __shared__ bf16 Bs[128 * 32];
  int tid = threadIdx.x;
  int lane = tid & 63, w = tid >> 6;
  int nwg = gridDim.x * gridDim.y;
  int bid = blockIdx.y * gridDim.x + blockIdx.x;
  int sw = (bid & 7) * (nwg >> 3) + (bid >> 3);
  int bx = sw % gridDim.x, by = sw / gridDim.x;
  int m0 = by * 128, n0 = bx * 128;
  int m_off = (w >> 1) * 64, n_off = (w & 1) * 64;
  f32x4 acc[4][4] = {};

  const char* Ab = (const char*)A;
  const char* Bb = (const char*)Bt;
  int srow = (lane >> 2);
  int skb  = (lane & 3) * 16;

  for (int k0 = 0; k0 < K; k0 += 32) {
    for (int j = 0; j < 2; j++) {
      int seg = j * 4 + w;
      int row = seg * 16 + srow;
      gload_lds16(Ab + ((size_t)(m0 + row) * K + k0) * 2 + skb, (char*)As + seg * 1024);
      gload_lds16(Bb + ((size_t)(n0 + row) * K + k0) * 2 + skb, (char*)Bs + seg * 1024);
    }
    __syncthreads();
    int rl = lane & 15;
    int kgb = (lane >> 4) * 16;
    bf16x8 a[4], b[4];
    for (int i = 0; i < 4; i++)
      a[i] = *(const bf16x8*)((const char*)As + (m_off + i * 16 + rl) * 64 + kgb);
    for (int i = 0; i < 4; i++)
      b[i] = *(const bf16x8*)((const char*)Bs + (n_off + i * 16 + rl) * 64 + kgb);
    for (int i = 0; i < 4; i++)
      for (int j = 0; j < 4; j++)
        acc[i][j] = __builtin_amdgcn_mfma_f32_16x16x32_bf16(a[i], b[j], acc[i][j], 0, 0, 0);
    __syncthreads();
  }

  int rq = (lane >> 4) * 4, cl = lane & 15;
  if constexpr (OUT_BF16) {
    bool rope = (n0 + n_off) < 2048;
    for (int i = 0; i < 4; i++)
      for (int r = 0; r < 4; r++) {
        int row = m0 + m_off + i * 16 + rq + r;
        int srw = row & 2047;
        if (rope) {
          for (int j = 0; j < 2; j++) {
            int d2 = j * 16 + cl;
            float c = cosT[srw * 32 + d2], sn = sinT[srw * 32 + d2];
            float x1 = acc[i][j][r], x2 = acc[i][j + 2][r];
            Cb[(size_t)row * N + n0 + n_off + d2]      = (bf16)(x1 * c - x2 * sn);
            Cb[(size_t)row * N + n0 + n_off + d2 + 32] = (bf16)(x2 * c + x1 * sn);
          }
        } else {
          for (int j = 0; j < 4; j++)
            Cb[(size_t)row * N + n0 + n_off + j * 16 + cl] = (bf16)acc[i][j][r];
        }
      }
  } else {
    for (int i = 0; i < 4; i++)
      for (int j = 0; j < 4; j++) {
        int col = n0 + n_off + j * 16 + cl;
        for (int r = 0; r < 4; r++) {
          int row = m0 + m_off + i * 16 + rq + r;
          Cf[(size_t)row * N + col] = acc[i][j][r] + bias[col];
        }
      }
  }
}

// ---------------- flash attention: 32x32 MFMA, lane-local softmax, shfl-verified ----------------
// grid: 512 blocks x 256 threads (4 waves); wave w owns 32 q-rows of a 128-row q-tile.
__global__ __launch_bounds__(256) void attn_kernel(const bf16* __restrict__ qkv,
                                                   const bf16* __restrict__ vt,
                                                   bf16* __restrict__ O) {
  __shared__ __align__(16) unsigned char Ks[2][8192];
  __shared__ __align__(16) unsigned char Vs[2][8192];
  int tid = threadIdx.x, lane = tid & 63, w = tid >> 6;
  int bid = blockIdx.x;
  int xcd = bid & 7, slot = bid >> 3;
  int bh = xcd * 4 + (slot & 3);
  int u = slot >> 2;
  int qt = (u < 8) ? (15 - u) : (u - 8);
  int b = bh >> 4, h = bh & 15;
  int q0w = qt * 128 + w * 32;
  int l31 = lane & 31, hi = lane >> 5;
  const char* qb = (const char*)qkv;
  const char* vb = (const char*)vt;

  // Q fragments (B-operand): lane holds Q[q0w+l31][d = s*16 + hi*8 + e], scale 1/8 folded (exact)
  bf16x8 aq[4];
#pragma unroll
  for (int s = 0; s < 4; s++) {
    size_t row = (size_t)(b * 2048 + q0w + l31);
    bf16x8 v = *(const bf16x8*)(qb + (row * 3072 + h * 64 + s * 16 + hi * 8) * 2);
#pragma unroll
    for (int e = 0; e < 8; e++) v[e] = (bf16)((float)v[e] * 0.125f);
    aq[s] = v;
  }

  f32x16 o0 = {}, o1 = {};
  float mrun = -3e38f, lrun = 0.f;

  // staging: 256 threads x (2 K + 2 V) 16B chunks; linear LDS dest, pre-swizzled source
  int r0 = tid >> 3, c0s = (tid & 7) ^ (r0 & 7);
  int r1 = r0 + 32;                      // (r1 & 7) == (r0 & 7) -> same chunk swizzle
  int ntiles = 2 * qt + 2;

  // prologue: stage tile 0 into buf 0
  gload_lds16(qb + (((size_t)(b * 2048 + r0) * 3072) + 1024 + h * 64) * 2 + c0s * 16, (char*)Ks[0] + tid * 16);
  gload_lds16(qb + (((size_t)(b * 2048 + r1) * 3072) + 1024 + h * 64) * 2 + c0s * 16, (char*)Ks[0] + (tid + 256) * 16);
  gload_lds16(vb + (((size_t)(bh * 64 + r0) * 2048)) * 2 + c0s * 16, (char*)Vs[0] + tid * 16);
  gload_lds16(vb + (((size_t)(bh * 64 + r1) * 2048)) * 2 + c0s * 16, (char*)Vs[0] + (tid + 256) * 16);
  asm volatile("s_waitcnt vmcnt(0)" ::: "memory");
  __builtin_amdgcn_s_barrier();

  for (int t = 0; t < ntiles; t++) {
    int kv0 = t * 64;
    int cur = t & 1;
    if (t + 1 < ntiles) {
      int kvn = kv0 + 64;
      gload_lds16(qb + (((size_t)(b * 2048 + kvn + r0) * 3072) + 1024 + h * 64) * 2 + c0s * 16, (char*)Ks[cur ^ 1] + tid * 16);
      gload_lds16(qb + (((size_t)(b * 2048 + kvn + r1) * 3072) + 1024 + h * 64) * 2 + c0s * 16, (char*)Ks[cur ^ 1] + (tid + 256) * 16);
      gload_lds16(vb + (((size_t)(bh * 64 + r0) * 2048) + kvn) * 2 + c0s * 16, (char*)Vs[cur ^ 1] + tid * 16);
      gload_lds16(vb + (((size_t)(bh * 64 + r1) * 2048) + kvn) * 2 + c0s * 16, (char*)Vs[cur ^ 1] + (tid + 256) * 16);
    }

    if (kv0 <= q0w + 31) {
      bool diag = (kv0 + 63 > q0w);

      // S^T: C[k][q], lane col = q = q0w + l31; row k = kv0 + kf*32 + crow(r,hi)
      f32x16 scr[2];
#pragma unroll
      for (int kf = 0; kf < 2; kf++)
#pragma unroll
        for (int r = 0; r < 16; r++) scr[kf][r] = 0.f;
#pragma unroll
      for (int s = 0; s < 4; s++) {
#pragma unroll
        for (int kf = 0; kf < 2; kf++) {
          int row = kf * 32 + l31;
          int ch = (hi + 2 * s) ^ (row & 7);
          bf16x8 ak = *(const bf16x8*)(Ks[cur] + row * 128 + ch * 16);
          scr[kf] = __builtin_amdgcn_mfma_f32_32x32x16_bf16(ak, aq[s], scr[kf], 0, 0, 0);
        }
      }

      int qg = q0w + l31;
      if (diag) {
#pragma unroll
        for (int kf = 0; kf < 2; kf++)
#pragma unroll
          for (int r = 0; r < 16; r++) {
            int k = kv0 + kf * 32 + (r & 3) + 8 * (r >> 2) + 4 * hi;
            if (k > qg) scr[kf][r] = -3e38f;
          }
      }

      // lane-local max over own 32 values + cross-half exchange (verified shfl)
      float mx = -3e38f;
#pragma unroll
      for (int kf = 0; kf < 2; kf++)
#pragma unroll
        for (int r = 0; r < 16; r++) mx = fmaxf(mx, scr[kf][r]);
      mx = fmaxf(mx, __shfl_xor(mx, 32));

      // T13 defer-max: rescale only when max grew by > 8
      if (!__all(mx - mrun <= 8.f)) {
        float mnew = fmaxf(mrun, mx);
        float corr = __expf(mrun - mnew);
        mrun = mnew;
        lrun *= corr;
#pragma unroll
        for (int r = 0; r < 16; r++) {
          float cr = __shfl(corr, (r & 3) + 8 * (r >> 2) + 4 * hi);
          o0[r] *= cr; o1[r] *= cr;
        }
      }

      // P = exp(S - mrun), pack adjacent crow pairs to bf16x2 dwords
      float rs = 0.f;
      unsigned D[2][8];
#pragma unroll
      for (int kf = 0; kf < 2; kf++)
#pragma unroll
        for (int j = 0; j < 8; j++) {
          float p0 = __expf(scr[kf][2 * j] - mrun);
          float p1 = __expf(scr[kf][2 * j + 1] - mrun);
          rs += p0 + p1;
          bf16x2 tp; tp[0] = (bf16)p0; tp[1] = (bf16)p1;
          D[kf][j] = __builtin_bit_cast(unsigned, tp);
        }
      rs += __shfl_xor(rs, 32);
      lrun += rs;

      // PV: A-frag slice (kf,sg) needs lane(hi) to hold P pairs k = sg*16 + hi*8 + {0..7}.
      // Own D-pairs (crow): hi=0 {(0,1),(2,3),(8,9),(10,11)}, hi=1 {(4,5),(6,7),(12,13),(14,15)} (+16sg).
      // Y = shfl_xor(hi?E0:E2): hi=0 <- (4,5), hi=1 <- (8,9).  Z likewise for odd dwords.
#pragma unroll
      for (int kf = 0; kf < 2; kf++) {
#pragma unroll
        for (int sg = 0; sg < 2; sg++) {
          unsigned E0 = D[kf][4 * sg + 0], E1 = D[kf][4 * sg + 1];
          unsigned E2 = D[kf][4 * sg + 2], E3 = D[kf][4 * sg + 3];
          unsigned Y = __shfl_xor(hi ? E0 : E2, 32);
          unsigned Z = __shfl_xor(hi ? E1 : E3, 32);
          union { unsigned u[4]; bf16x8 v; } ap;
          ap.u[0] = hi ? Y : E0;
          ap.u[1] = hi ? Z : E1;
          ap.u[2] = hi ? E2 : Y;
          ap.u[3] = hi ? E3 : Z;
#pragma unroll
          for (int nf = 0; nf < 2; nf++) {
            int row = nf * 32 + l31;
            int ch = (hi + 2 * sg + 4 * kf) ^ (row & 7);
            bf16x8 bv = *(const bf16x8*)(Vs[cur] + row * 128 + ch * 16);
            if (nf == 0) o0 = __builtin_amdgcn_mfma_f32_32x32x16_bf16(ap.v, bv, o0, 0, 0, 0);
            else         o1 = __builtin_amdgcn_mfma_f32_32x32x16_bf16(ap.v, bv, o1, 0, 0, 0);
          }
        }
      }
    }

    asm volatile("s_waitcnt vmcnt(0)" ::: "memory");
    __builtin_amdgcn_s_barrier();
  }

  // epilogue: normalize, write O[q][h*64 + nf*32 + l31]
  float linv = 1.0f / lrun;
#pragma unroll
  for (int r = 0; r < 16; r++) {
    int crow = (r & 3) + 8 * (r >> 2) + 4 * hi;
    float lr = __shfl(linv, crow);
    size_t row = (size_t)(b * 2048 + q0w + crow);
    O[row * 1024 + h * 64 + l31]      = (bf16)(o0[r] * lr);
    O[row * 1024 + h * 64 + 32 + l31] = (bf16)(o1[r] * lr);
  }
}

extern "C" void kernel_launch(void* const* d_in, const int* in_sizes, int n_in,
                              void* d_out, int out_size, void* d_ws, size_t ws_size,
                              hipStream_t stream) {
  const float* x      = (const float*)d_in[0];
  const float* w_qkv  = (const float*)d_in[1];
  const float* w_proj = (const float*)d_in[2];
  const float* b_proj = (const float*)d_in[3];

  char* ws = (char*)d_ws;
  size_t off = 0;
  bf16* xb     = (bf16*)(ws + off); off += (size_t)M_ * D_ * 2;
  bf16* wqkvT  = (bf16*)(ws + off); off += (size_t)N3_ * D_ * 2;
  bf16* wprojT = (bf16*)(ws + off); off += (size_t)D_ * D_ * 2;
  bf16* qkvb   = (bf16*)(ws + off); off += (size_t)M_ * N3_ * 2;
  bf16* ob     = (bf16*)(ws + off); off += (size_t)M_ * D_ * 2;
  bf16* vtb    = (bf16*)(ws + off); off += (size_t)M_ * D_ * 2;
  float* cosT  = (float*)(ws + off); off += (size_t)S_ * 32 * 4;
  float* sinT  = (float*)(ws + off); off += (size_t)S_ * 32 * 4;

  conv_f32_bf16<<<(M_ * D_ / 4 + 255) / 256, 256, 0, stream>>>(x, xb, M_ * D_ / 4);
  transpose_to_bf16<<<dim3(N3_ / 32, D_ / 32), dim3(32, 8), 0, stream>>>(w_qkv, wqkvT, D_, N3_);
  transpose_to_bf16<<<dim3(D_ / 32, D_ / 32), dim3(32, 8), 0, stream>>>(w_proj, wprojT, D_, D_);
  rope_table<<<(S_ * 32) / 256, 256, 0, stream>>>(cosT, sinT);
  gemm128<true><<<dim3(N3_ / 128, M_ / 128), 256, 0, stream>>>(xb, wqkvT, M_, N3_, D_, qkvb, nullptr, nullptr, cosT, sinT);
  transpose_v<<<dim3(S_ / 32, B_ * D_ / 32), dim3(32, 8), 0, stream>>>(qkvb, vtb);
  attn_kernel<<<512, 256, 0, stream>>>(qkvb, vtb, ob);
  gemm128<false><<<dim3(D_ / 128, M_ / 128), 256, 0, stream>>>(ob, wprojT, M_, D_, D_, nullptr, (float*)d_out, b_proj, nullptr, nullptr);
}

// Round 7
// 135.084 us; speedup vs baseline: 1.5581x; 1.0578x over previous
//
#include <hip/hip_runtime.h>
#include <stdint.h>
#include <math.h>

#define B_   2
#define S_   2048
#define D_   1024
#define H_   16
#define HD_  64
#define M_   (B_*S_)     // 4096
#define N3_  (3*D_)      // 3072

typedef __bf16 bf16;
typedef __bf16 bf16x2 __attribute__((ext_vector_type(2)));
typedef __bf16 bf16x4v __attribute__((ext_vector_type(4)));
typedef __bf16 bf16x8 __attribute__((ext_vector_type(8)));
typedef float  f32x4 __attribute__((ext_vector_type(4)));
typedef float  f32x16 __attribute__((ext_vector_type(16)));

__device__ __forceinline__ void gload_lds16(const void* g, void* l) {
  __builtin_amdgcn_global_load_lds(
      (__attribute__((address_space(1))) const unsigned int*)g,
      (__attribute__((address_space(3))) unsigned int*)l, 16, 0, 0);
}

// ---------------- convert x fp32 -> bf16 ----------------
__global__ __launch_bounds__(256) void conv_f32_bf16(const float* __restrict__ in,
                                                     bf16* __restrict__ out, int n4) {
  int i = blockIdx.x * 256 + threadIdx.x;
  if (i < n4) {
    float4 v = ((const float4*)in)[i];
    bf16x4v o;
    o[0] = (bf16)v.x; o[1] = (bf16)v.y; o[2] = (bf16)v.z; o[3] = (bf16)v.w;
    *(bf16x4v*)(out + (size_t)i * 4) = o;
  }
}

// ---------------- transpose fp32 [R][C] -> bf16 [C][R] ----------------
__global__ __launch_bounds__(256) void transpose_to_bf16(const float* __restrict__ in,
                                                         bf16* __restrict__ out, int R, int C) {
  __shared__ bf16 tile[32][33];
  int c0 = blockIdx.x * 32, r0 = blockIdx.y * 32;
  int tx = threadIdx.x, ty = threadIdx.y;   // 32 x 8
  for (int j = 0; j < 4; j++) {
    int r = r0 + ty + j * 8;
    tile[ty + j * 8][tx] = (bf16)in[(size_t)r * C + c0 + tx];
  }
  __syncthreads();
  for (int j = 0; j < 4; j++) {
    int c = c0 + ty + j * 8;
    out[(size_t)c * R + r0 + tx] = tile[tx][ty + j * 8];
  }
}

// ---------------- transpose V: qkv v-part [B*S][D] -> vt [(b*16+h)*64+d][S] ----------------
__global__ __launch_bounds__(256) void transpose_v(const bf16* __restrict__ qkv,
                                                   bf16* __restrict__ vt) {
  __shared__ bf16 tile[32][33];
  int s0 = blockIdx.x * 32;
  int c0 = blockIdx.y * 32;
  int tx = threadIdx.x, ty = threadIdx.y;
  for (int j = 0; j < 4; j++) {
    int s = s0 + ty + j * 8;
    int c = c0 + tx;
    int b = c >> 10, hd = c & 1023;
    tile[ty + j * 8][tx] = qkv[((size_t)(b * 2048 + s)) * 3072 + 2048 + hd];
  }
  __syncthreads();
  for (int j = 0; j < 4; j++) {
    int c = c0 + ty + j * 8;
    int b = c >> 10, hd = c & 1023;
    vt[((size_t)(b * 1024 + hd)) * 2048 + s0 + tx] = tile[tx][ty + j * 8];
  }
}

// ---------------- RoPE table ----------------
__global__ __launch_bounds__(256) void rope_table(float* __restrict__ cosT, float* __restrict__ sinT) {
  int i = blockIdx.x * 256 + threadIdx.x;   // < 2048*32
  int s = i >> 5, d = i & 31;
  float inv = powf(10000.0f, -(float)d * (1.0f / 32.0f));
  float a = (float)s * inv;
  float sv, cv;
  sincosf(a, &sv, &cv);
  cosT[i] = cv; sinT[i] = sv;
}

// ---------------- GEMM: C[M][N] = A[M][K] * Bt[N][K]^T ----------------
template<bool OUT_BF16>
__global__ __launch_bounds__(256) void gemm128(const bf16* __restrict__ A,
                                               const bf16* __restrict__ Bt,
                                               int M, int N, int K,
                                               bf16* __restrict__ Cb,
                                               float* __restrict__ Cf,
                                               const float* __restrict__ bias,
                                               const float* __restrict__ cosT,
                                               const float* __restrict__ sinT) {
  __shared__ bf16 As[128 * 32];
  __shared__ bf16 Bs[128 * 32];
  int tid = threadIdx.x;
  int lane = tid & 63, w = tid >> 6;
  int nwg = gridDim.x * gridDim.y;
  int bid = blockIdx.y * gridDim.x + blockIdx.x;
  int sw = (bid & 7) * (nwg >> 3) + (bid >> 3);
  int bx = sw % gridDim.x, by = sw / gridDim.x;
  int m0 = by * 128, n0 = bx * 128;
  int m_off = (w >> 1) * 64, n_off = (w & 1) * 64;
  f32x4 acc[4][4] = {};

  const char* Ab = (const char*)A;
  const char* Bb = (const char*)Bt;
  int srow = (lane >> 2);
  int skb  = (lane & 3) * 16;

  for (int k0 = 0; k0 < K; k0 += 32) {
    for (int j = 0; j < 2; j++) {
      int seg = j * 4 + w;
      int row = seg * 16 + srow;
      gload_lds16(Ab + ((size_t)(m0 + row) * K + k0) * 2 + skb, (char*)As + seg * 1024);
      gload_lds16(Bb + ((size_t)(n0 + row) * K + k0) * 2 + skb, (char*)Bs + seg * 1024);
    }
    __syncthreads();
    int rl = lane & 15;
    int kgb = (lane >> 4) * 16;
    bf16x8 a[4], b[4];
    for (int i = 0; i < 4; i++)
      a[i] = *(const bf16x8*)((const char*)As + (m_off + i * 16 + rl) * 64 + kgb);
    for (int i = 0; i < 4; i++)
      b[i] = *(const bf16x8*)((const char*)Bs + (n_off + i * 16 + rl) * 64 + kgb);
    for (int i = 0; i < 4; i++)
      for (int j = 0; j < 4; j++)
        acc[i][j] = __builtin_amdgcn_mfma_f32_16x16x32_bf16(a[i], b[j], acc[i][j], 0, 0, 0);
    __syncthreads();
  }

  int rq = (lane >> 4) * 4, cl = lane & 15;
  if constexpr (OUT_BF16) {
    bool rope = (n0 + n_off) < 2048;
    for (int i = 0; i < 4; i++)
      for (int r = 0; r < 4; r++) {
        int row = m0 + m_off + i * 16 + rq + r;
        int srw = row & 2047;
        if (rope) {
          for (int j = 0; j < 2; j++) {
            int d2 = j * 16 + cl;
            float c = cosT[srw * 32 + d2], sn = sinT[srw * 32 + d2];
            float x1 = acc[i][j][r], x2 = acc[i][j + 2][r];
            Cb[(size_t)row * N + n0 + n_off + d2]      = (bf16)(x1 * c - x2 * sn);
            Cb[(size_t)row * N + n0 + n_off + d2 + 32] = (bf16)(x2 * c + x1 * sn);
          }
        } else {
          for (int j = 0; j < 4; j++)
            Cb[(size_t)row * N + n0 + n_off + j * 16 + cl] = (bf16)acc[i][j][r];
        }
      }
  } else {
    for (int i = 0; i < 4; i++)
      for (int j = 0; j < 4; j++) {
        int col = n0 + n_off + j * 16 + cl;
        for (int r = 0; r < 4; r++) {
          int row = m0 + m_off + i * 16 + rq + r;
          Cf[(size_t)row * N + col] = acc[i][j][r] + bias[col];
        }
      }
  }
}

// ---------------- flash attention: 8 waves = 4 q-subtiles x 2 kv-parities ----------------
// grid: 512 blocks x 512 threads; wave (qw,p): 32 q-rows, kv tiles i*128 + p*64.
__global__ __launch_bounds__(512, 4) void attn_kernel(const bf16* __restrict__ qkv,
                                                      const bf16* __restrict__ vt,
                                                      bf16* __restrict__ O) {
  __shared__ __align__(16) unsigned char Ks[2][16384];  // [128 s][64 d] bf16
  __shared__ __align__(16) unsigned char Vs[2][16384];  // [64 d][128 s] bf16
  int tid = threadIdx.x, lane = tid & 63, w = tid >> 6;
  int qw = w & 3, p = w >> 2;
  int bid = blockIdx.x;
  int xcd = bid & 7, slot = bid >> 3;
  int bh = xcd * 4 + (slot & 3);
  int u = slot >> 2;
  int qt = (u < 8) ? (15 - u) : (u - 8);
  int b = bh >> 4, h = bh & 15;
  int q0w = qt * 128 + qw * 32;
  int l31 = lane & 31, hi = lane >> 5;
  const char* qb = (const char*)qkv;
  const char* vb = (const char*)vt;

  // Q fragments (B-operand): lane holds Q[q0w+l31][d = s*16 + hi*8 + e]
  // scale = 1/8 * log2(e) folded (exp2 domain)
  bf16x8 aq[4];
#pragma unroll
  for (int s = 0; s < 4; s++) {
    size_t row = (size_t)(b * 2048 + q0w + l31);
    bf16x8 v = *(const bf16x8*)(qb + (row * 3072 + h * 64 + s * 16 + hi * 8) * 2);
#pragma unroll
    for (int e = 0; e < 8; e++) v[e] = (bf16)((float)v[e] * 0.18033688f);
    aq[s] = v;
  }

  f32x16 o0 = {}, o1 = {};
  float mrun = -3e38f, lrun = 0.f;

  // staging indices: K rows kr0=tid>>3 (+64), chunk kc=tid&7; V rows vr0=tid>>4 (+32), chunk vc=tid&15
  int kr0 = tid >> 3, kcs = (tid & 7) ^ (kr0 & 7);
  int vr0 = tid >> 4, vcs = (tid & 15) ^ (vr0 & 7);
  int npair = qt + 1;

#define STAGE(buf, kvbase)                                                                              \
  do {                                                                                                  \
    gload_lds16(qb + (((size_t)(b * 2048 + (kvbase) + kr0) * 3072) + 1024 + h * 64) * 2 + kcs * 16,     \
                (char*)Ks[buf] + tid * 16);                                                             \
    gload_lds16(qb + (((size_t)(b * 2048 + (kvbase) + kr0 + 64) * 3072) + 1024 + h * 64) * 2 + kcs * 16,\
                (char*)Ks[buf] + (tid + 512) * 16);                                                     \
    gload_lds16(vb + (((size_t)(bh * 64 + vr0) * 2048) + (kvbase)) * 2 + vcs * 16,                      \
                (char*)Vs[buf] + tid * 16);                                                             \
    gload_lds16(vb + (((size_t)(bh * 64 + vr0 + 32) * 2048) + (kvbase)) * 2 + vcs * 16,                 \
                (char*)Vs[buf] + (tid + 512) * 16);                                                     \
  } while (0)

  STAGE(0, 0);
  asm volatile("s_waitcnt vmcnt(0)" ::: "memory");
  __builtin_amdgcn_s_barrier();

  for (int i = 0; i < npair; i++) {
    int cur = i & 1;
    if (i + 1 < npair) STAGE(cur ^ 1, (i + 1) * 128);

    int kvw = i * 128 + p * 64;
    if (kvw <= q0w + 31) {
      bool diag = (kvw + 63 > q0w);

      // S^T: C[k][q], lane col = q = q0w + l31; row k = kvw + kf*32 + crow(r,hi)
      f32x16 scr[2];
#pragma unroll
      for (int kf = 0; kf < 2; kf++)
#pragma unroll
        for (int r = 0; r < 16; r++) scr[kf][r] = 0.f;
      __builtin_amdgcn_s_setprio(1);
#pragma unroll
      for (int s = 0; s < 4; s++) {
#pragma unroll
        for (int kf = 0; kf < 2; kf++) {
          int row = p * 64 + kf * 32 + l31;
          int ch = (hi + 2 * s) ^ (row & 7);
          bf16x8 ak = *(const bf16x8*)(Ks[cur] + row * 128 + ch * 16);
          scr[kf] = __builtin_amdgcn_mfma_f32_32x32x16_bf16(ak, aq[s], scr[kf], 0, 0, 0);
        }
      }
      __builtin_amdgcn_s_setprio(0);

      int qg = q0w + l31;
      if (diag) {
#pragma unroll
        for (int kf = 0; kf < 2; kf++)
#pragma unroll
          for (int r = 0; r < 16; r++) {
            int k = kvw + kf * 32 + (r & 3) + 8 * (r >> 2) + 4 * hi;
            if (k > qg) scr[kf][r] = -3e38f;
          }
      }

      // lane-local max over own 32 values + cross-half exchange
      float mx = -3e38f;
#pragma unroll
      for (int kf = 0; kf < 2; kf++)
#pragma unroll
        for (int r = 0; r < 16; r++) mx = fmaxf(mx, scr[kf][r]);
      mx = fmaxf(mx, __shfl_xor(mx, 32));

      // T13 defer-max (log2 domain): rescale only when max grew by > ~8 nats
      if (!__all(mx - mrun <= 11.5f)) {
        float mnew = fmaxf(mrun, mx);
        float corr = exp2f(mrun - mnew);
        mrun = mnew;
        lrun *= corr;
#pragma unroll
        for (int r = 0; r < 16; r++) {
          float cr = __shfl(corr, (r & 3) + 8 * (r >> 2) + 4 * hi);
          o0[r] *= cr; o1[r] *= cr;
        }
      }

      // P = exp2(S' - mrun), pack adjacent crow pairs to bf16x2 dwords
      float rs = 0.f;
      unsigned D[2][8];
#pragma unroll
      for (int kf = 0; kf < 2; kf++)
#pragma unroll
        for (int j = 0; j < 8; j++) {
          float p0 = exp2f(scr[kf][2 * j] - mrun);
          float p1 = exp2f(scr[kf][2 * j + 1] - mrun);
          rs += p0 + p1;
          bf16x2 tp; tp[0] = (bf16)p0; tp[1] = (bf16)p1;
          D[kf][j] = __builtin_bit_cast(unsigned, tp);
        }
      rs += __shfl_xor(rs, 32);
      lrun += rs;

      // PV: A-frag slice (kf,sg) needs lane(hi) to hold P pairs k = sg*16 + hi*8 + {0..7}
#pragma unroll
      for (int kf = 0; kf < 2; kf++) {
#pragma unroll
        for (int sg = 0; sg < 2; sg++) {
          unsigned E0 = D[kf][4 * sg + 0], E1 = D[kf][4 * sg + 1];
          unsigned E2 = D[kf][4 * sg + 2], E3 = D[kf][4 * sg + 3];
          unsigned Y = __shfl_xor(hi ? E0 : E2, 32);
          unsigned Z = __shfl_xor(hi ? E1 : E3, 32);
          union { unsigned u[4]; bf16x8 v; } ap;
          ap.u[0] = hi ? Y : E0;
          ap.u[1] = hi ? Z : E1;
          ap.u[2] = hi ? E2 : Y;
          ap.u[3] = hi ? E3 : Z;
          __builtin_amdgcn_s_setprio(1);
#pragma unroll
          for (int nf = 0; nf < 2; nf++) {
            int row = nf * 32 + l31;
            int ch = ((p * 8) + (hi + 2 * sg + 4 * kf)) ^ (row & 7);
            bf16x8 bv = *(const bf16x8*)(Vs[cur] + row * 256 + ch * 16);
            if (nf == 0) o0 = __builtin_amdgcn_mfma_f32_32x32x16_bf16(ap.v, bv, o0, 0, 0, 0);
            else         o1 = __builtin_amdgcn_mfma_f32_32x32x16_bf16(ap.v, bv, o1, 0, 0, 0);
          }
          __builtin_amdgcn_s_setprio(0);
        }
      }
    }

    asm volatile("s_waitcnt vmcnt(0)" ::: "memory");
    __builtin_amdgcn_s_barrier();
  }

  // ---- cross-parity combine (reuse staging LDS) ----
  float* mlb = (float*)Ks;   // [qw][p][{m,l}][32]
  if (hi == 0) {
    mlb[((qw * 2 + p) * 2 + 0) * 32 + l31] = mrun;
    mlb[((qw * 2 + p) * 2 + 1) * 32 + l31] = lrun;
  }
  __syncthreads();
  float m_o = mlb[((qw * 2 + (1 - p)) * 2 + 0) * 32 + l31];
  float l_o = mlb[((qw * 2 + (1 - p)) * 2 + 1) * 32 + l31];
  float Mm = fmaxf(mrun, m_o);
  float cs = exp2f(mrun - Mm);
  float L  = lrun * cs + l_o * exp2f(m_o - Mm);
  float* obuf = (float*)Vs;  // [qw][32 r][64 lane]
  if (p == 1) {
#pragma unroll
    for (int r = 0; r < 16; r++) {
      int crow = (r & 3) + 8 * (r >> 2) + 4 * hi;
      float c = __shfl(cs, crow);
      obuf[qw * 2048 + r * 64 + lane]        = o0[r] * c;
      obuf[qw * 2048 + (r + 16) * 64 + lane] = o1[r] * c;
    }
  }
  __syncthreads();
  if (p == 0) {
    float linv = 1.0f / L;
#pragma unroll
    for (int r = 0; r < 16; r++) {
      int crow = (r & 3) + 8 * (r >> 2) + 4 * hi;
      float c  = __shfl(cs, crow);
      float li = __shfl(linv, crow);
      size_t row = (size_t)(b * 2048 + q0w + crow);
      float v0 = (o0[r] * c + obuf[qw * 2048 + r * 64 + lane]) * li;
      float v1 = (o1[r] * c + obuf[qw * 2048 + (r + 16) * 64 + lane]) * li;
      O[row * 1024 + h * 64 + l31]      = (bf16)v0;
      O[row * 1024 + h * 64 + 32 + l31] = (bf16)v1;
    }
  }
#undef STAGE
}

extern "C" void kernel_launch(void* const* d_in, const int* in_sizes, int n_in,
                              void* d_out, int out_size, void* d_ws, size_t ws_size,
                              hipStream_t stream) {
  const float* x      = (const float*)d_in[0];
  const float* w_qkv  = (const float*)d_in[1];
  const float* w_proj = (const float*)d_in[2];
  const float* b_proj = (const float*)d_in[3];

  char* ws = (char*)d_ws;
  size_t off = 0;
  bf16* xb     = (bf16*)(ws + off); off += (size_t)M_ * D_ * 2;
  bf16* wqkvT  = (bf16*)(ws + off); off += (size_t)N3_ * D_ * 2;
  bf16* wprojT = (bf16*)(ws + off); off += (size_t)D_ * D_ * 2;
  bf16* qkvb   = (bf16*)(ws + off); off += (size_t)M_ * N3_ * 2;
  bf16* ob     = (bf16*)(ws + off); off += (size_t)M_ * D_ * 2;
  bf16* vtb    = (bf16*)(ws + off); off += (size_t)M_ * D_ * 2;
  float* cosT  = (float*)(ws + off); off += (size_t)S_ * 32 * 4;
  float* sinT  = (float*)(ws + off); off += (size_t)S_ * 32 * 4;

  conv_f32_bf16<<<(M_ * D_ / 4 + 255) / 256, 256, 0, stream>>>(x, xb, M_ * D_ / 4);
  transpose_to_bf16<<<dim3(N3_ / 32, D_ / 32), dim3(32, 8), 0, stream>>>(w_qkv, wqkvT, D_, N3_);
  transpose_to_bf16<<<dim3(D_ / 32, D_ / 32), dim3(32, 8), 0, stream>>>(w_proj, wprojT, D_, D_);
  rope_table<<<(S_ * 32) / 256, 256, 0, stream>>>(cosT, sinT);
  gemm128<true><<<dim3(N3_ / 128, M_ / 128), 256, 0, stream>>>(xb, wqkvT, M_, N3_, D_, qkvb, nullptr, nullptr, cosT, sinT);
  transpose_v<<<dim3(S_ / 32, B_ * D_ / 32), dim3(32, 8), 0, stream>>>(qkvb, vtb);
  attn_kernel<<<512, 512, 0, stream>>>(qkvb, vtb, ob);
  gemm128<false><<<dim3(D_ / 128, M_ / 128), 256, 0, stream>>>(ob, wprojT, M_, D_, D_, nullptr, (float*)d_out, b_proj, nullptr, nullptr);
}

// Round 8
// 133.311 us; speedup vs baseline: 1.5788x; 1.0133x over previous
//
#include <hip/hip_runtime.h>
#include <stdint.h>
#include <math.h>

#define B_   2
#define S_   2048
#define D_   1024
#define H_   16
#define HD_  64
#define M_   (B_*S_)     // 4096
#define N3_  (3*D_)      // 3072

typedef __bf16 bf16;
typedef __bf16 bf16x2 __attribute__((ext_vector_type(2)));
typedef __bf16 bf16x4v __attribute__((ext_vector_type(4)));
typedef __bf16 bf16x8 __attribute__((ext_vector_type(8)));
typedef float  f32x4 __attribute__((ext_vector_type(4)));
typedef float  f32x16 __attribute__((ext_vector_type(16)));

__device__ __forceinline__ void gload_lds16(const void* g, void* l) {
  __builtin_amdgcn_global_load_lds(
      (__attribute__((address_space(1))) const unsigned int*)g,
      (__attribute__((address_space(3))) unsigned int*)l, 16, 0, 0);
}

// ---------------- convert x fp32 -> bf16 ----------------
__global__ __launch_bounds__(256) void conv_f32_bf16(const float* __restrict__ in,
                                                     bf16* __restrict__ out, int n4) {
  int i = blockIdx.x * 256 + threadIdx.x;
  if (i < n4) {
    float4 v = ((const float4*)in)[i];
    bf16x4v o;
    o[0] = (bf16)v.x; o[1] = (bf16)v.y; o[2] = (bf16)v.z; o[3] = (bf16)v.w;
    *(bf16x4v*)(out + (size_t)i * 4) = o;
  }
}

// ---------------- transpose fp32 [R][C] -> bf16 [C][R] ----------------
__global__ __launch_bounds__(256) void transpose_to_bf16(const float* __restrict__ in,
                                                         bf16* __restrict__ out, int R, int C) {
  __shared__ bf16 tile[32][33];
  int c0 = blockIdx.x * 32, r0 = blockIdx.y * 32;
  int tx = threadIdx.x, ty = threadIdx.y;   // 32 x 8
  for (int j = 0; j < 4; j++) {
    int r = r0 + ty + j * 8;
    tile[ty + j * 8][tx] = (bf16)in[(size_t)r * C + c0 + tx];
  }
  __syncthreads();
  for (int j = 0; j < 4; j++) {
    int c = c0 + ty + j * 8;
    out[(size_t)c * R + r0 + tx] = tile[tx][ty + j * 8];
  }
}

// ---------------- RoPE table ----------------
__global__ __launch_bounds__(256) void rope_table(float* __restrict__ cosT, float* __restrict__ sinT) {
  int i = blockIdx.x * 256 + threadIdx.x;   // < 2048*32
  int s = i >> 5, d = i & 31;
  float inv = powf(10000.0f, -(float)d * (1.0f / 32.0f));
  float a = (float)s * inv;
  float sv, cv;
  sincosf(a, &sv, &cv);
  cosT[i] = cv; sinT[i] = sv;
}

// ---------------- GEMM: C[M][N] = A[M][K] * Bt[N][K]^T ----------------
// OUT_BF16: q/k cols -> RoPE fused into qkvb; v cols -> sigma-permuted V^T into vt.
template<bool OUT_BF16>
__global__ __launch_bounds__(256) void gemm128(const bf16* __restrict__ A,
                                               const bf16* __restrict__ Bt,
                                               int M, int N, int K,
                                               bf16* __restrict__ Cb,
                                               float* __restrict__ Cf,
                                               const float* __restrict__ bias,
                                               const float* __restrict__ cosT,
                                               const float* __restrict__ sinT,
                                               bf16* __restrict__ vt) {
  __shared__ bf16 As[128 * 32];
  __shared__ bf16 Bs[128 * 32];
  int tid = threadIdx.x;
  int lane = tid & 63, w = tid >> 6;
  int nwg = gridDim.x * gridDim.y;
  int bid = blockIdx.y * gridDim.x + blockIdx.x;
  int sw = (bid & 7) * (nwg >> 3) + (bid >> 3);
  int bx = sw % gridDim.x, by = sw / gridDim.x;
  int m0 = by * 128, n0 = bx * 128;
  int m_off = (w >> 1) * 64, n_off = (w & 1) * 64;
  f32x4 acc[4][4] = {};

  const char* Ab = (const char*)A;
  const char* Bb = (const char*)Bt;
  int srow = (lane >> 2);
  int skb  = (lane & 3) * 16;

  for (int k0 = 0; k0 < K; k0 += 32) {
    for (int j = 0; j < 2; j++) {
      int seg = j * 4 + w;
      int row = seg * 16 + srow;
      gload_lds16(Ab + ((size_t)(m0 + row) * K + k0) * 2 + skb, (char*)As + seg * 1024);
      gload_lds16(Bb + ((size_t)(n0 + row) * K + k0) * 2 + skb, (char*)Bs + seg * 1024);
    }
    __syncthreads();
    int rl = lane & 15;
    int kgb = (lane >> 4) * 16;
    bf16x8 a[4], b[4];
    for (int i = 0; i < 4; i++)
      a[i] = *(const bf16x8*)((const char*)As + (m_off + i * 16 + rl) * 64 + kgb);
    for (int i = 0; i < 4; i++)
      b[i] = *(const bf16x8*)((const char*)Bs + (n_off + i * 16 + rl) * 64 + kgb);
    for (int i = 0; i < 4; i++)
      for (int j = 0; j < 4; j++)
        acc[i][j] = __builtin_amdgcn_mfma_f32_16x16x32_bf16(a[i], b[j], acc[i][j], 0, 0, 0);
    __syncthreads();
  }

  int rq = (lane >> 4) * 4, cl = lane & 15;
  if constexpr (OUT_BF16) {
    if ((n0 + n_off) < 2048) {        // q/k region: RoPE fused
      for (int i = 0; i < 4; i++)
        for (int r = 0; r < 4; r++) {
          int row = m0 + m_off + i * 16 + rq + r;
          int srw = row & 2047;
          for (int j = 0; j < 2; j++) {
            int d2 = j * 16 + cl;
            float c = cosT[srw * 32 + d2], sn = sinT[srw * 32 + d2];
            float x1 = acc[i][j][r], x2 = acc[i][j + 2][r];
            Cb[(size_t)row * N + n0 + n_off + d2]      = (bf16)(x1 * c - x2 * sn);
            Cb[(size_t)row * N + n0 + n_off + d2 + 32] = (bf16)(x2 * c + x1 * sn);
          }
        }
    } else {                          // v region: write sigma-permuted V^T
      int posbase = ((rq & 4) << 1) | ((rq & 8) >> 1);
      for (int i = 0; i < 4; i++) {
        int row0 = m0 + m_off + i * 16;        // 16-aligned s-group base
        int b = row0 >> 11;
        int sbase = (row0 & 2047) + posbase;
        for (int j = 0; j < 4; j++) {
          int col = n0 + n_off + j * 16 + cl - 2048;   // b_hd in [0,1024)
          bf16x4v pv;
          pv[0] = (bf16)acc[i][j][0]; pv[1] = (bf16)acc[i][j][1];
          pv[2] = (bf16)acc[i][j][2]; pv[3] = (bf16)acc[i][j][3];
          *(bf16x4v*)(vt + ((size_t)(b * 1024 + col)) * 2048 + sbase) = pv;
        }
      }
    }
  } else {
    for (int i = 0; i < 4; i++)
      for (int j = 0; j < 4; j++) {
        int col = n0 + n_off + j * 16 + cl;
        for (int r = 0; r < 4; r++) {
          int row = m0 + m_off + i * 16 + rq + r;
          Cf[(size_t)row * N + col] = acc[i][j][r] + bias[col];
        }
      }
  }
}

// ---------------- flash attention: 256 blocks x 2 balanced tasks, zero-shuffle PV ----------------
// block: bh fixed; tasks qt=u and qt=15-u (17 pair-iterations total, scheduler-independent).
// 8 waves = 4 q-subtiles x 2 kv-parities; wave owns 32 q-rows.
__global__ __launch_bounds__(512, 4) void attn_kernel(const bf16* __restrict__ qkv,
                                                      const bf16* __restrict__ vt,
                                                      bf16* __restrict__ O) {
  __shared__ __align__(16) unsigned char Ks[2][16384];  // [128 s][64 d] bf16
  __shared__ __align__(16) unsigned char Vs[2][16384];  // [64 d][128 s-perm] bf16
  int tid = threadIdx.x, lane = tid & 63, w = tid >> 6;
  int qw = w & 3, p = w >> 2;
  int bid = blockIdx.x;
  int xcd = bid & 7;
  int bh = xcd * 4 + ((bid >> 3) & 3);
  int u = bid >> 5;                       // 0..7
  int b = bh >> 4, h = bh & 15;
  int l31 = lane & 31, hi = lane >> 5;
  const char* qb = (const char*)qkv;
  const char* vb = (const char*)vt;

  int kr0 = tid >> 3, kcs = (tid & 7) ^ (kr0 & 7);
  int vr0 = tid >> 4, vcs = (tid & 15) ^ (vr0 & 7);

#define STAGE(buf, kvbase)                                                                              \
  do {                                                                                                  \
    gload_lds16(qb + (((size_t)(b * 2048 + (kvbase) + kr0) * 3072) + 1024 + h * 64) * 2 + kcs * 16,     \
                (char*)Ks[buf] + tid * 16);                                                             \
    gload_lds16(qb + (((size_t)(b * 2048 + (kvbase) + kr0 + 64) * 3072) + 1024 + h * 64) * 2 + kcs * 16,\
                (char*)Ks[buf] + (tid + 512) * 16);                                                     \
    gload_lds16(vb + (((size_t)(bh * 64 + vr0) * 2048) + (kvbase)) * 2 + vcs * 16,                      \
                (char*)Vs[buf] + tid * 16);                                                             \
    gload_lds16(vb + (((size_t)(bh * 64 + vr0 + 32) * 2048) + (kvbase)) * 2 + vcs * 16,                 \
                (char*)Vs[buf] + (tid + 512) * 16);                                                     \
  } while (0)

  for (int task = 0; task < 2; task++) {
    int qt = task ? (15 - u) : u;
    int q0w = qt * 128 + qw * 32;

    // Q fragments (B-operand), scale = 1/8 * log2(e) folded (exp2 domain)
    bf16x8 aq[4];
#pragma unroll
    for (int s = 0; s < 4; s++) {
      size_t row = (size_t)(b * 2048 + q0w + l31);
      bf16x8 v = *(const bf16x8*)(qb + (row * 3072 + h * 64 + s * 16 + hi * 8) * 2);
#pragma unroll
      for (int e = 0; e < 8; e++) v[e] = (bf16)((float)v[e] * 0.18033688f);
      aq[s] = v;
    }

    f32x16 o0 = {}, o1 = {};
    float mrun = -3e38f, lrun = 0.f;
    int npair = qt + 1;

    __syncthreads();   // protect LDS from previous task's combine
    STAGE(0, 0);
    asm volatile("s_waitcnt vmcnt(0)" ::: "memory");
    __builtin_amdgcn_s_barrier();

    for (int i = 0; i < npair; i++) {
      int cur = i & 1;
      if (i + 1 < npair) STAGE(cur ^ 1, (i + 1) * 128);

      int kvw = i * 128 + p * 64;
      if (kvw <= q0w + 31) {
        bool diag = (kvw + 63 > q0w);

        // S^T: C[k][q], lane col = q = q0w + l31; row k = kvw + kf*32 + crow(r,hi)
        f32x16 scr[2];
#pragma unroll
        for (int kf = 0; kf < 2; kf++)
#pragma unroll
          for (int r = 0; r < 16; r++) scr[kf][r] = 0.f;
        __builtin_amdgcn_s_setprio(1);
#pragma unroll
        for (int s = 0; s < 4; s++) {
#pragma unroll
          for (int kf = 0; kf < 2; kf++) {
            int row = p * 64 + kf * 32 + l31;
            int ch = (hi + 2 * s) ^ (row & 7);
            bf16x8 ak = *(const bf16x8*)(Ks[cur] + row * 128 + ch * 16);
            scr[kf] = __builtin_amdgcn_mfma_f32_32x32x16_bf16(ak, aq[s], scr[kf], 0, 0, 0);
          }
        }
        __builtin_amdgcn_s_setprio(0);

        int qg = q0w + l31;
        if (diag) {
#pragma unroll
          for (int kf = 0; kf < 2; kf++)
#pragma unroll
            for (int r = 0; r < 16; r++) {
              int k = kvw + kf * 32 + (r & 3) + 8 * (r >> 2) + 4 * hi;
              if (k > qg) scr[kf][r] = -3e38f;
            }
        }

        float mx = -3e38f;
#pragma unroll
        for (int kf = 0; kf < 2; kf++)
#pragma unroll
          for (int r = 0; r < 16; r++) mx = fmaxf(mx, scr[kf][r]);
        mx = fmaxf(mx, __shfl_xor(mx, 32));

        // T13 defer-max
        if (!__all(mx - mrun <= 11.5f)) {
          float mnew = fmaxf(mrun, mx);
          float corr = exp2f(mrun - mnew);
          mrun = mnew;
          lrun *= corr;
#pragma unroll
          for (int r = 0; r < 16; r++) {
            float cr = __shfl(corr, (r & 3) + 8 * (r >> 2) + 4 * hi);
            o0[r] *= cr; o1[r] *= cr;
          }
        }

        // P = exp2(S' - mrun), pack adjacent crow pairs
        float rs = 0.f;
        unsigned D[2][8];
#pragma unroll
        for (int kf = 0; kf < 2; kf++)
#pragma unroll
          for (int j = 0; j < 8; j++) {
            float p0 = exp2f(scr[kf][2 * j] - mrun);
            float p1 = exp2f(scr[kf][2 * j + 1] - mrun);
            rs += p0 + p1;
            bf16x2 tp; tp[0] = (bf16)p0; tp[1] = (bf16)p1;
            D[kf][j] = __builtin_bit_cast(unsigned, tp);
          }
        rs += __shfl_xor(rs, 32);
        lrun += rs;

        // PV: sigma-permuted V makes D dwords the A-fragment directly (no shuffles)
#pragma unroll
        for (int kf = 0; kf < 2; kf++) {
#pragma unroll
          for (int sg = 0; sg < 2; sg++) {
            union { unsigned u4[4]; bf16x8 v; } ap;
            ap.u4[0] = D[kf][4 * sg + 0];
            ap.u4[1] = D[kf][4 * sg + 1];
            ap.u4[2] = D[kf][4 * sg + 2];
            ap.u4[3] = D[kf][4 * sg + 3];
            __builtin_amdgcn_s_setprio(1);
#pragma unroll
            for (int nf = 0; nf < 2; nf++) {
              int row = nf * 32 + l31;
              int ch = ((p * 8) + (hi + 2 * sg + 4 * kf)) ^ (row & 7);
              bf16x8 bv = *(const bf16x8*)(Vs[cur] + row * 256 + ch * 16);
              if (nf == 0) o0 = __builtin_amdgcn_mfma_f32_32x32x16_bf16(ap.v, bv, o0, 0, 0, 0);
              else         o1 = __builtin_amdgcn_mfma_f32_32x32x16_bf16(ap.v, bv, o1, 0, 0, 0);
            }
            __builtin_amdgcn_s_setprio(0);
          }
        }
      }

      asm volatile("s_waitcnt vmcnt(0)" ::: "memory");
      __builtin_amdgcn_s_barrier();
    }

    // ---- cross-parity combine (reuse staging LDS) ----
    float* mlb = (float*)Ks;   // [qw][p][{m,l}][32]
    if (hi == 0) {
      mlb[((qw * 2 + p) * 2 + 0) * 32 + l31] = mrun;
      mlb[((qw * 2 + p) * 2 + 1) * 32 + l31] = lrun;
    }
    __syncthreads();
    float m_o = mlb[((qw * 2 + (1 - p)) * 2 + 0) * 32 + l31];
    float l_o = mlb[((qw * 2 + (1 - p)) * 2 + 1) * 32 + l31];
    float Mm = fmaxf(mrun, m_o);
    float cs = exp2f(mrun - Mm);
    float L  = lrun * cs + l_o * exp2f(m_o - Mm);
    float* obuf = (float*)Vs;  // [qw][32 r][64 lane]
    if (p == 1) {
#pragma unroll
      for (int r = 0; r < 16; r++) {
        int crow = (r & 3) + 8 * (r >> 2) + 4 * hi;
        float c = __shfl(cs, crow);
        obuf[qw * 2048 + r * 64 + lane]        = o0[r] * c;
        obuf[qw * 2048 + (r + 16) * 64 + lane] = o1[r] * c;
      }
    }
    __syncthreads();
    if (p == 0) {
      float linv = 1.0f / L;
#pragma unroll
      for (int r = 0; r < 16; r++) {
        int crow = (r & 3) + 8 * (r >> 2) + 4 * hi;
        float c  = __shfl(cs, crow);
        float li = __shfl(linv, crow);
        size_t row = (size_t)(b * 2048 + q0w + crow);
        float v0 = (o0[r] * c + obuf[qw * 2048 + r * 64 + lane]) * li;
        float v1 = (o1[r] * c + obuf[qw * 2048 + (r + 16) * 64 + lane]) * li;
        O[row * 1024 + h * 64 + l31]      = (bf16)v0;
        O[row * 1024 + h * 64 + 32 + l31] = (bf16)v1;
      }
    }
  }
#undef STAGE
}

extern "C" void kernel_launch(void* const* d_in, const int* in_sizes, int n_in,
                              void* d_out, int out_size, void* d_ws, size_t ws_size,
                              hipStream_t stream) {
  const float* x      = (const float*)d_in[0];
  const float* w_qkv  = (const float*)d_in[1];
  const float* w_proj = (const float*)d_in[2];
  const float* b_proj = (const float*)d_in[3];

  char* ws = (char*)d_ws;
  size_t off = 0;
  bf16* xb     = (bf16*)(ws + off); off += (size_t)M_ * D_ * 2;
  bf16* wqkvT  = (bf16*)(ws + off); off += (size_t)N3_ * D_ * 2;
  bf16* wprojT = (bf16*)(ws + off); off += (size_t)D_ * D_ * 2;
  bf16* qkvb   = (bf16*)(ws + off); off += (size_t)M_ * N3_ * 2;
  bf16* ob     = (bf16*)(ws + off); off += (size_t)M_ * D_ * 2;
  bf16* vtb    = (bf16*)(ws + off); off += (size_t)M_ * D_ * 2;
  float* cosT  = (float*)(ws + off); off += (size_t)S_ * 32 * 4;
  float* sinT  = (float*)(ws + off); off += (size_t)S_ * 32 * 4;

  conv_f32_bf16<<<(M_ * D_ / 4 + 255) / 256, 256, 0, stream>>>(x, xb, M_ * D_ / 4);
  transpose_to_bf16<<<dim3(N3_ / 32, D_ / 32), dim3(32, 8), 0, stream>>>(w_qkv, wqkvT, D_, N3_);
  transpose_to_bf16<<<dim3(D_ / 32, D_ / 32), dim3(32, 8), 0, stream>>>(w_proj, wprojT, D_, D_);
  rope_table<<<(S_ * 32) / 256, 256, 0, stream>>>(cosT, sinT);
  gemm128<true><<<dim3(N3_ / 128, M_ / 128), 256, 0, stream>>>(xb, wqkvT, M_, N3_, D_, qkvb, nullptr, nullptr, cosT, sinT, vtb);
  attn_kernel<<<256, 512, 0, stream>>>(qkvb, vtb, ob);
  gemm128<false><<<dim3(D_ / 128, M_ / 128), 256, 0, stream>>>(ob, wprojT, M_, D_, D_, nullptr, (float*)d_out, b_proj, nullptr, nullptr, nullptr);
}

// Round 9
// 126.513 us; speedup vs baseline: 1.6637x; 1.0537x over previous
//
#include <hip/hip_runtime.h>
#include <stdint.h>
#include <math.h>

#define B_   2
#define S_   2048
#define D_   1024
#define H_   16
#define HD_  64
#define M_   (B_*S_)     // 4096
#define N3_  (3*D_)      // 3072

typedef __bf16 bf16;
typedef __bf16 bf16x2 __attribute__((ext_vector_type(2)));
typedef __bf16 bf16x4v __attribute__((ext_vector_type(4)));
typedef __bf16 bf16x8 __attribute__((ext_vector_type(8)));
typedef float  f32x4 __attribute__((ext_vector_type(4)));
typedef float  f32x16 __attribute__((ext_vector_type(16)));

__device__ __forceinline__ void gload_lds16(const void* g, void* l) {
  __builtin_amdgcn_global_load_lds(
      (__attribute__((address_space(1))) const unsigned int*)g,
      (__attribute__((address_space(3))) unsigned int*)l, 16, 0, 0);
}

// ---------------- convert x fp32 -> bf16 ----------------
__global__ __launch_bounds__(256) void conv_f32_bf16(const float* __restrict__ in,
                                                     bf16* __restrict__ out, int n4) {
  int i = blockIdx.x * 256 + threadIdx.x;
  if (i < n4) {
    float4 v = ((const float4*)in)[i];
    bf16x4v o;
    o[0] = (bf16)v.x; o[1] = (bf16)v.y; o[2] = (bf16)v.z; o[3] = (bf16)v.w;
    *(bf16x4v*)(out + (size_t)i * 4) = o;
  }
}

// ---------------- transpose fp32 [R][C] -> bf16 [C][R] ----------------
__global__ __launch_bounds__(256) void transpose_to_bf16(const float* __restrict__ in,
                                                         bf16* __restrict__ out, int R, int C) {
  __shared__ bf16 tile[32][33];
  int c0 = blockIdx.x * 32, r0 = blockIdx.y * 32;
  int tx = threadIdx.x, ty = threadIdx.y;   // 32 x 8
  for (int j = 0; j < 4; j++) {
    int r = r0 + ty + j * 8;
    tile[ty + j * 8][tx] = (bf16)in[(size_t)r * C + c0 + tx];
  }
  __syncthreads();
  for (int j = 0; j < 4; j++) {
    int c = c0 + ty + j * 8;
    out[(size_t)c * R + r0 + tx] = tile[tx][ty + j * 8];
  }
}

// ---------------- RoPE table ----------------
__global__ __launch_bounds__(256) void rope_table(float* __restrict__ cosT, float* __restrict__ sinT) {
  int i = blockIdx.x * 256 + threadIdx.x;   // < 2048*32
  int s = i >> 5, d = i & 31;
  float inv = powf(10000.0f, -(float)d * (1.0f / 32.0f));
  float a = (float)s * inv;
  float sv, cv;
  sincosf(a, &sv, &cv);
  cosT[i] = cv; sinT[i] = sv;
}

// ---------------- GEMM: C[M][N] = A[M][K] * Bt[N][K]^T ----------------
// OUT_BF16: q/k cols -> RoPE fused into qkvb; v cols -> sigma-permuted V^T into vt.
template<bool OUT_BF16>
__global__ __launch_bounds__(256) void gemm128(const bf16* __restrict__ A,
                                               const bf16* __restrict__ Bt,
                                               int M, int N, int K,
                                               bf16* __restrict__ Cb,
                                               float* __restrict__ Cf,
                                               const float* __restrict__ bias,
                                               const float* __restrict__ cosT,
                                               const float* __restrict__ sinT,
                                               bf16* __restrict__ vt) {
  __shared__ bf16 As[128 * 32];
  __shared__ bf16 Bs[128 * 32];
  int tid = threadIdx.x;
  int lane = tid & 63, w = tid >> 6;
  int nwg = gridDim.x * gridDim.y;
  int bid = blockIdx.y * gridDim.x + blockIdx.x;
  int sw = (bid & 7) * (nwg >> 3) + (bid >> 3);
  int bx = sw % gridDim.x, by = sw / gridDim.x;
  int m0 = by * 128, n0 = bx * 128;
  int m_off = (w >> 1) * 64, n_off = (w & 1) * 64;
  f32x4 acc[4][4] = {};

  const char* Ab = (const char*)A;
  const char* Bb = (const char*)Bt;
  int srow = (lane >> 2);
  int skb  = (lane & 3) * 16;

  for (int k0 = 0; k0 < K; k0 += 32) {
    for (int j = 0; j < 2; j++) {
      int seg = j * 4 + w;
      int row = seg * 16 + srow;
      gload_lds16(Ab + ((size_t)(m0 + row) * K + k0) * 2 + skb, (char*)As + seg * 1024);
      gload_lds16(Bb + ((size_t)(n0 + row) * K + k0) * 2 + skb, (char*)Bs + seg * 1024);
    }
    __syncthreads();
    int rl = lane & 15;
    int kgb = (lane >> 4) * 16;
    bf16x8 a[4], b[4];
    for (int i = 0; i < 4; i++)
      a[i] = *(const bf16x8*)((const char*)As + (m_off + i * 16 + rl) * 64 + kgb);
    for (int i = 0; i < 4; i++)
      b[i] = *(const bf16x8*)((const char*)Bs + (n_off + i * 16 + rl) * 64 + kgb);
    for (int i = 0; i < 4; i++)
      for (int j = 0; j < 4; j++)
        acc[i][j] = __builtin_amdgcn_mfma_f32_16x16x32_bf16(a[i], b[j], acc[i][j], 0, 0, 0);
    __syncthreads();
  }

  int rq = (lane >> 4) * 4, cl = lane & 15;
  if constexpr (OUT_BF16) {
    if ((n0 + n_off) < 2048) {        // q/k region: RoPE fused
      for (int i = 0; i < 4; i++)
        for (int r = 0; r < 4; r++) {
          int row = m0 + m_off + i * 16 + rq + r;
          int srw = row & 2047;
          for (int j = 0; j < 2; j++) {
            int d2 = j * 16 + cl;
            float c = cosT[srw * 32 + d2], sn = sinT[srw * 32 + d2];
            float x1 = acc[i][j][r], x2 = acc[i][j + 2][r];
            Cb[(size_t)row * N + n0 + n_off + d2]      = (bf16)(x1 * c - x2 * sn);
            Cb[(size_t)row * N + n0 + n_off + d2 + 32] = (bf16)(x2 * c + x1 * sn);
          }
        }
    } else {                          // v region: write sigma-permuted V^T
      int posbase = ((rq & 4) << 1) | ((rq & 8) >> 1);
      for (int i = 0; i < 4; i++) {
        int row0 = m0 + m_off + i * 16;        // 16-aligned s-group base
        int b = row0 >> 11;
        int sbase = (row0 & 2047) + posbase;
        for (int j = 0; j < 4; j++) {
          int col = n0 + n_off + j * 16 + cl - 2048;   // b_hd in [0,1024)
          bf16x4v pv;
          pv[0] = (bf16)acc[i][j][0]; pv[1] = (bf16)acc[i][j][1];
          pv[2] = (bf16)acc[i][j][2]; pv[3] = (bf16)acc[i][j][3];
          *(bf16x4v*)(vt + ((size_t)(b * 1024 + col)) * 2048 + sbase) = pv;
        }
      }
    }
  } else {
    for (int i = 0; i < 4; i++)
      for (int j = 0; j < 4; j++) {
        int col = n0 + n_off + j * 16 + cl;
        for (int r = 0; r < 4; r++) {
          int row = m0 + m_off + i * 16 + rq + r;
          Cf[(size_t)row * N + col] = acc[i][j][r] + bias[col];
        }
      }
  }
}

// ---------------- flash attention: 512 blocks, LPT order (qt = 15-u), zero-shuffle PV ----------------
// 8 waves = 4 q-subtiles x 2 kv-parities; wave owns 32 q-rows of a 128-row q-tile.
__global__ __launch_bounds__(512, 4) void attn_kernel(const bf16* __restrict__ qkv,
                                                      const bf16* __restrict__ vt,
                                                      bf16* __restrict__ O) {
  __shared__ __align__(16) unsigned char Ks[2][16384];  // [128 s][64 d] bf16
  __shared__ __align__(16) unsigned char Vs[2][16384];  // [64 d][128 s-perm] bf16
  int tid = threadIdx.x, lane = tid & 63, w = tid >> 6;
  int qw = w & 3, p = w >> 2;
  int bid = blockIdx.x;
  int xcd = bid & 7, slot = bid >> 3;
  int bh = xcd * 4 + (slot & 3);
  int u = slot >> 2;                       // 0..15, increasing with bid
  int qt = 15 - u;                         // LPT: heaviest jobs dispatched first, strictly decreasing
  int b = bh >> 4, h = bh & 15;
  int q0w = qt * 128 + qw * 32;
  int l31 = lane & 31, hi = lane >> 5;
  const char* qb = (const char*)qkv;
  const char* vb = (const char*)vt;

  int kr0 = tid >> 3, kcs = (tid & 7) ^ (kr0 & 7);
  int vr0 = tid >> 4, vcs = (tid & 15) ^ (vr0 & 7);

#define STAGE(buf, kvbase)                                                                              \
  do {                                                                                                  \
    gload_lds16(qb + (((size_t)(b * 2048 + (kvbase) + kr0) * 3072) + 1024 + h * 64) * 2 + kcs * 16,     \
                (char*)Ks[buf] + tid * 16);                                                             \
    gload_lds16(qb + (((size_t)(b * 2048 + (kvbase) + kr0 + 64) * 3072) + 1024 + h * 64) * 2 + kcs * 16,\
                (char*)Ks[buf] + (tid + 512) * 16);                                                     \
    gload_lds16(vb + (((size_t)(bh * 64 + vr0) * 2048) + (kvbase)) * 2 + vcs * 16,                      \
                (char*)Vs[buf] + tid * 16);                                                             \
    gload_lds16(vb + (((size_t)(bh * 64 + vr0 + 32) * 2048) + (kvbase)) * 2 + vcs * 16,                 \
                (char*)Vs[buf] + (tid + 512) * 16);                                                     \
  } while (0)

  // Q fragments (B-operand), scale = 1/8 * log2(e) folded (exp2 domain)
  bf16x8 aq[4];
#pragma unroll
  for (int s = 0; s < 4; s++) {
    size_t row = (size_t)(b * 2048 + q0w + l31);
    bf16x8 v = *(const bf16x8*)(qb + (row * 3072 + h * 64 + s * 16 + hi * 8) * 2);
#pragma unroll
    for (int e = 0; e < 8; e++) v[e] = (bf16)((float)v[e] * 0.18033688f);
    aq[s] = v;
  }

  f32x16 o0 = {}, o1 = {};
  float mrun = -3e38f, lrun = 0.f;
  int npair = qt + 1;

  STAGE(0, 0);
  asm volatile("s_waitcnt vmcnt(0)" ::: "memory");
  __builtin_amdgcn_s_barrier();

  for (int i = 0; i < npair; i++) {
    int cur = i & 1;
    if (i + 1 < npair) STAGE(cur ^ 1, (i + 1) * 128);

    int kvw = i * 128 + p * 64;
    if (kvw <= q0w + 31) {
      bool diag = (kvw + 63 > q0w);

      // S^T: C[k][q], lane col = q = q0w + l31; row k = kvw + kf*32 + crow(r,hi)
      f32x16 scr[2];
#pragma unroll
      for (int kf = 0; kf < 2; kf++)
#pragma unroll
        for (int r = 0; r < 16; r++) scr[kf][r] = 0.f;
      __builtin_amdgcn_s_setprio(1);
#pragma unroll
      for (int s = 0; s < 4; s++) {
#pragma unroll
        for (int kf = 0; kf < 2; kf++) {
          int row = p * 64 + kf * 32 + l31;
          int ch = (hi + 2 * s) ^ (row & 7);
          bf16x8 ak = *(const bf16x8*)(Ks[cur] + row * 128 + ch * 16);
          scr[kf] = __builtin_amdgcn_mfma_f32_32x32x16_bf16(ak, aq[s], scr[kf], 0, 0, 0);
        }
      }
      __builtin_amdgcn_s_setprio(0);

      int qg = q0w + l31;
      if (diag) {
#pragma unroll
        for (int kf = 0; kf < 2; kf++)
#pragma unroll
          for (int r = 0; r < 16; r++) {
            int k = kvw + kf * 32 + (r & 3) + 8 * (r >> 2) + 4 * hi;
            if (k > qg) scr[kf][r] = -3e38f;
          }
      }

      float mx = -3e38f;
#pragma unroll
      for (int kf = 0; kf < 2; kf++)
#pragma unroll
        for (int r = 0; r < 16; r++) mx = fmaxf(mx, scr[kf][r]);
      mx = fmaxf(mx, __shfl_xor(mx, 32));

      // T13 defer-max
      if (!__all(mx - mrun <= 11.5f)) {
        float mnew = fmaxf(mrun, mx);
        float corr = exp2f(mrun - mnew);
        mrun = mnew;
        lrun *= corr;
#pragma unroll
        for (int r = 0; r < 16; r++) {
          float cr = __shfl(corr, (r & 3) + 8 * (r >> 2) + 4 * hi);
          o0[r] *= cr; o1[r] *= cr;
        }
      }

      // P = exp2(S' - mrun), pack adjacent crow pairs
      float rs = 0.f;
      unsigned D[2][8];
#pragma unroll
      for (int kf = 0; kf < 2; kf++)
#pragma unroll
        for (int j = 0; j < 8; j++) {
          float p0 = exp2f(scr[kf][2 * j] - mrun);
          float p1 = exp2f(scr[kf][2 * j + 1] - mrun);
          rs += p0 + p1;
          bf16x2 tp; tp[0] = (bf16)p0; tp[1] = (bf16)p1;
          D[kf][j] = __builtin_bit_cast(unsigned, tp);
        }
      rs += __shfl_xor(rs, 32);
      lrun += rs;

      // PV: sigma-permuted V makes D dwords the A-fragment directly (no shuffles)
#pragma unroll
      for (int kf = 0; kf < 2; kf++) {
#pragma unroll
        for (int sg = 0; sg < 2; sg++) {
          union { unsigned u4[4]; bf16x8 v; } ap;
          ap.u4[0] = D[kf][4 * sg + 0];
          ap.u4[1] = D[kf][4 * sg + 1];
          ap.u4[2] = D[kf][4 * sg + 2];
          ap.u4[3] = D[kf][4 * sg + 3];
          __builtin_amdgcn_s_setprio(1);
#pragma unroll
          for (int nf = 0; nf < 2; nf++) {
            int row = nf * 32 + l31;
            int ch = ((p * 8) + (hi + 2 * sg + 4 * kf)) ^ (row & 7);
            bf16x8 bv = *(const bf16x8*)(Vs[cur] + row * 256 + ch * 16);
            if (nf == 0) o0 = __builtin_amdgcn_mfma_f32_32x32x16_bf16(ap.v, bv, o0, 0, 0, 0);
            else         o1 = __builtin_amdgcn_mfma_f32_32x32x16_bf16(ap.v, bv, o1, 0, 0, 0);
          }
          __builtin_amdgcn_s_setprio(0);
        }
      }
    }

    asm volatile("s_waitcnt vmcnt(0)" ::: "memory");
    __builtin_amdgcn_s_barrier();
  }

  // ---- cross-parity combine (reuse staging LDS) ----
  float* mlb = (float*)Ks;   // [qw][p][{m,l}][32]
  if (hi == 0) {
    mlb[((qw * 2 + p) * 2 + 0) * 32 + l31] = mrun;
    mlb[((qw * 2 + p) * 2 + 1) * 32 + l31] = lrun;
  }
  __syncthreads();
  float m_o = mlb[((qw * 2 + (1 - p)) * 2 + 0) * 32 + l31];
  float l_o = mlb[((qw * 2 + (1 - p)) * 2 + 1) * 32 + l31];
  float Mm = fmaxf(mrun, m_o);
  float cs = exp2f(mrun - Mm);
  float L  = lrun * cs + l_o * exp2f(m_o - Mm);
  float* obuf = (float*)Vs;  // [qw][32 r][64 lane]
  if (p == 1) {
#pragma unroll
    for (int r = 0; r < 16; r++) {
      int crow = (r & 3) + 8 * (r >> 2) + 4 * hi;
      float c = __shfl(cs, crow);
      obuf[qw * 2048 + r * 64 + lane]        = o0[r] * c;
      obuf[qw * 2048 + (r + 16) * 64 + lane] = o1[r] * c;
    }
  }
  __syncthreads();
  if (p == 0) {
    float linv = 1.0f / L;
#pragma unroll
    for (int r = 0; r < 16; r++) {
      int crow = (r & 3) + 8 * (r >> 2) + 4 * hi;
      float c  = __shfl(cs, crow);
      float li = __shfl(linv, crow);
      size_t row = (size_t)(b * 2048 + q0w + crow);
      float v0 = (o0[r] * c + obuf[qw * 2048 + r * 64 + lane]) * li;
      float v1 = (o1[r] * c + obuf[qw * 2048 + (r + 16) * 64 + lane]) * li;
      O[row * 1024 + h * 64 + l31]      = (bf16)v0;
      O[row * 1024 + h * 64 + 32 + l31] = (bf16)v1;
    }
  }
#undef STAGE
}

extern "C" void kernel_launch(void* const* d_in, const int* in_sizes, int n_in,
                              void* d_out, int out_size, void* d_ws, size_t ws_size,
                              hipStream_t stream) {
  const float* x      = (const float*)d_in[0];
  const float* w_qkv  = (const float*)d_in[1];
  const float* w_proj = (const float*)d_in[2];
  const float* b_proj = (const float*)d_in[3];

  char* ws = (char*)d_ws;
  size_t off = 0;
  bf16* xb     = (bf16*)(ws + off); off += (size_t)M_ * D_ * 2;
  bf16* wqkvT  = (bf16*)(ws + off); off += (size_t)N3_ * D_ * 2;
  bf16* wprojT = (bf16*)(ws + off); off += (size_t)D_ * D_ * 2;
  bf16* qkvb   = (bf16*)(ws + off); off += (size_t)M_ * N3_ * 2;
  bf16* ob     = (bf16*)(ws + off); off += (size_t)M_ * D_ * 2;
  bf16* vtb    = (bf16*)(ws + off); off += (size_t)M_ * D_ * 2;
  float* cosT  = (float*)(ws + off); off += (size_t)S_ * 32 * 4;
  float* sinT  = (float*)(ws + off); off += (size_t)S_ * 32 * 4;

  conv_f32_bf16<<<(M_ * D_ / 4 + 255) / 256, 256, 0, stream>>>(x, xb, M_ * D_ / 4);
  transpose_to_bf16<<<dim3(N3_ / 32, D_ / 32), dim3(32, 8), 0, stream>>>(w_qkv, wqkvT, D_, N3_);
  transpose_to_bf16<<<dim3(D_ / 32, D_ / 32), dim3(32, 8), 0, stream>>>(w_proj, wprojT, D_, D_);
  rope_table<<<(S_ * 32) / 256, 256, 0, stream>>>(cosT, sinT);
  gemm128<true><<<dim3(N3_ / 128, M_ / 128), 256, 0, stream>>>(xb, wqkvT, M_, N3_, D_, qkvb, nullptr, nullptr, cosT, sinT, vtb);
  attn_kernel<<<512, 512, 0, stream>>>(qkvb, vtb, ob);
  gemm128<false><<<dim3(D_ / 128, M_ / 128), 256, 0, stream>>>(ob, wprojT, M_, D_, D_, nullptr, (float*)d_out, b_proj, nullptr, nullptr, nullptr);
}

// Round 10
// 121.311 us; speedup vs baseline: 1.7350x; 1.0429x over previous
//
#include <hip/hip_runtime.h>
#include <stdint.h>
#include <math.h>

#define B_   2
#define S_   2048
#define D_   1024
#define H_   16
#define HD_  64
#define M_   (B_*S_)     // 4096
#define N3_  (3*D_)      // 3072

typedef __bf16 bf16;
typedef __bf16 bf16x2 __attribute__((ext_vector_type(2)));
typedef __bf16 bf16x4v __attribute__((ext_vector_type(4)));
typedef __bf16 bf16x8 __attribute__((ext_vector_type(8)));
typedef float  f32x4 __attribute__((ext_vector_type(4)));
typedef float  f32x16 __attribute__((ext_vector_type(16)));

__device__ __forceinline__ void gload_lds16(const void* g, void* l) {
  __builtin_amdgcn_global_load_lds(
      (__attribute__((address_space(1))) const unsigned int*)g,
      (__attribute__((address_space(3))) unsigned int*)l, 16, 0, 0);
}

// ---------------- convert x fp32 -> bf16 ----------------
__global__ __launch_bounds__(256) void conv_f32_bf16(const float* __restrict__ in,
                                                     bf16* __restrict__ out, int n4) {
  int i = blockIdx.x * 256 + threadIdx.x;
  if (i < n4) {
    float4 v = ((const float4*)in)[i];
    bf16x4v o;
    o[0] = (bf16)v.x; o[1] = (bf16)v.y; o[2] = (bf16)v.z; o[3] = (bf16)v.w;
    *(bf16x4v*)(out + (size_t)i * 4) = o;
  }
}

// ---------------- transpose fp32 [R][C] -> bf16 [C][R] ----------------
__global__ __launch_bounds__(256) void transpose_to_bf16(const float* __restrict__ in,
                                                         bf16* __restrict__ out, int R, int C) {
  __shared__ bf16 tile[32][33];
  int c0 = blockIdx.x * 32, r0 = blockIdx.y * 32;
  int tx = threadIdx.x, ty = threadIdx.y;   // 32 x 8
  for (int j = 0; j < 4; j++) {
    int r = r0 + ty + j * 8;
    tile[ty + j * 8][tx] = (bf16)in[(size_t)r * C + c0 + tx];
  }
  __syncthreads();
  for (int j = 0; j < 4; j++) {
    int c = c0 + ty + j * 8;
    out[(size_t)c * R + r0 + tx] = tile[tx][ty + j * 8];
  }
}

// ---------------- RoPE table ----------------
__global__ __launch_bounds__(256) void rope_table(float* __restrict__ cosT, float* __restrict__ sinT) {
  int i = blockIdx.x * 256 + threadIdx.x;   // < 2048*32
  int s = i >> 5, d = i & 31;
  float inv = powf(10000.0f, -(float)d * (1.0f / 32.0f));
  float a = (float)s * inv;
  float sv, cv;
  sincosf(a, &sv, &cv);
  cosT[i] = cv; sinT[i] = sv;
}

// ---------------- GEMM: C[M][N] = A[M][K] * Bt[N][K]^T (128x128 tiles) ----------------
// q/k cols -> RoPE fused into qkvb; v cols -> sigma-permuted V^T into vt.
__global__ __launch_bounds__(256) void gemm128(const bf16* __restrict__ A,
                                               const bf16* __restrict__ Bt,
                                               int M, int N, int K,
                                               bf16* __restrict__ Cb,
                                               const float* __restrict__ cosT,
                                               const float* __restrict__ sinT,
                                               bf16* __restrict__ vt) {
  __shared__ bf16 As[128 * 32];
  __shared__ bf16 Bs[128 * 32];
  int tid = threadIdx.x;
  int lane = tid & 63, w = tid >> 6;
  int nwg = gridDim.x * gridDim.y;
  int bid = blockIdx.y * gridDim.x + blockIdx.x;
  int sw = (bid & 7) * (nwg >> 3) + (bid >> 3);
  int bx = sw % gridDim.x, by = sw / gridDim.x;
  int m0 = by * 128, n0 = bx * 128;
  int m_off = (w >> 1) * 64, n_off = (w & 1) * 64;
  f32x4 acc[4][4] = {};

  const char* Ab = (const char*)A;
  const char* Bb = (const char*)Bt;
  int srow = (lane >> 2);
  int skb  = (lane & 3) * 16;

  for (int k0 = 0; k0 < K; k0 += 32) {
    for (int j = 0; j < 2; j++) {
      int seg = j * 4 + w;
      int row = seg * 16 + srow;
      gload_lds16(Ab + ((size_t)(m0 + row) * K + k0) * 2 + skb, (char*)As + seg * 1024);
      gload_lds16(Bb + ((size_t)(n0 + row) * K + k0) * 2 + skb, (char*)Bs + seg * 1024);
    }
    __syncthreads();
    int rl = lane & 15;
    int kgb = (lane >> 4) * 16;
    bf16x8 a[4], b[4];
    for (int i = 0; i < 4; i++)
      a[i] = *(const bf16x8*)((const char*)As + (m_off + i * 16 + rl) * 64 + kgb);
    for (int i = 0; i < 4; i++)
      b[i] = *(const bf16x8*)((const char*)Bs + (n_off + i * 16 + rl) * 64 + kgb);
    for (int i = 0; i < 4; i++)
      for (int j = 0; j < 4; j++)
        acc[i][j] = __builtin_amdgcn_mfma_f32_16x16x32_bf16(a[i], b[j], acc[i][j], 0, 0, 0);
    __syncthreads();
  }

  int rq = (lane >> 4) * 4, cl = lane & 15;
  if ((n0 + n_off) < 2048) {        // q/k region: RoPE fused
    for (int i = 0; i < 4; i++)
      for (int r = 0; r < 4; r++) {
        int row = m0 + m_off + i * 16 + rq + r;
        int srw = row & 2047;
        for (int j = 0; j < 2; j++) {
          int d2 = j * 16 + cl;
          float c = cosT[srw * 32 + d2], sn = sinT[srw * 32 + d2];
          float x1 = acc[i][j][r], x2 = acc[i][j + 2][r];
          Cb[(size_t)row * N + n0 + n_off + d2]      = (bf16)(x1 * c - x2 * sn);
          Cb[(size_t)row * N + n0 + n_off + d2 + 32] = (bf16)(x2 * c + x1 * sn);
        }
      }
  } else {                          // v region: write sigma-permuted V^T
    int posbase = ((rq & 4) << 1) | ((rq & 8) >> 1);
    for (int i = 0; i < 4; i++) {
      int row0 = m0 + m_off + i * 16;        // 16-aligned s-group base
      int b = row0 >> 11;
      int sbase = (row0 & 2047) + posbase;
      for (int j = 0; j < 4; j++) {
        int col = n0 + n_off + j * 16 + cl - 2048;   // b_hd in [0,1024)
        bf16x4v pv;
        pv[0] = (bf16)acc[i][j][0]; pv[1] = (bf16)acc[i][j][1];
        pv[2] = (bf16)acc[i][j][2]; pv[3] = (bf16)acc[i][j][3];
        *(bf16x4v*)(vt + ((size_t)(b * 1024 + col)) * 2048 + sbase) = pv;
      }
    }
  }
}

// ---------------- proj GEMM: C[4096][1024] = A[4096][1024] * Bt[1024][1024]^T + bias ----------------
// BM=64, BN=128 -> grid (8,64) = 512 blocks (2/CU) for latency hiding.
__global__ __launch_bounds__(256) void gemm_proj(const bf16* __restrict__ A,
                                                 const bf16* __restrict__ Bt,
                                                 float* __restrict__ Cf,
                                                 const float* __restrict__ bias) {
  __shared__ bf16 As[64 * 32];
  __shared__ bf16 Bs[128 * 32];
  const int K = 1024, N = 1024;
  int tid = threadIdx.x;
  int lane = tid & 63, w = tid >> 6;
  int bid = blockIdx.y * gridDim.x + blockIdx.x;   // nwg = 512
  int sw = (bid & 7) * 64 + (bid >> 3);
  int bx = sw & 7, by = sw >> 3;
  int m0 = by * 64, n0 = bx * 128;
  int m_off = (w >> 1) * 32, n_off = (w & 1) * 64;
  f32x4 acc[2][4] = {};

  const char* Ab = (const char*)A;
  const char* Bb = (const char*)Bt;
  int arow = tid >> 2, achk = (tid & 3) * 16;

  for (int k0 = 0; k0 < K; k0 += 32) {
    gload_lds16(Ab + ((size_t)(m0 + arow) * K + k0) * 2 + achk, (char*)As + tid * 16);
    gload_lds16(Bb + ((size_t)(n0 + arow) * K + k0) * 2 + achk, (char*)Bs + tid * 16);
    gload_lds16(Bb + ((size_t)(n0 + 64 + arow) * K + k0) * 2 + achk, (char*)Bs + 4096 + tid * 16);
    __syncthreads();
    int rl = lane & 15;
    int kgb = (lane >> 4) * 16;
    bf16x8 a[2], b[4];
    for (int i = 0; i < 2; i++)
      a[i] = *(const bf16x8*)((const char*)As + (m_off + i * 16 + rl) * 64 + kgb);
    for (int j = 0; j < 4; j++)
      b[j] = *(const bf16x8*)((const char*)Bs + (n_off + j * 16 + rl) * 64 + kgb);
    for (int i = 0; i < 2; i++)
      for (int j = 0; j < 4; j++)
        acc[i][j] = __builtin_amdgcn_mfma_f32_16x16x32_bf16(a[i], b[j], acc[i][j], 0, 0, 0);
    __syncthreads();
  }

  int rq = (lane >> 4) * 4, cl = lane & 15;
  for (int i = 0; i < 2; i++)
    for (int j = 0; j < 4; j++) {
      int col = n0 + n_off + j * 16 + cl;
      float bv = bias[col];
      for (int r = 0; r < 4; r++) {
        int row = m0 + m_off + i * 16 + rq + r;
        Cf[(size_t)row * N + col] = acc[i][j][r] + bv;
      }
    }
}

// ---------------- flash attention: 512 blocks, LPT, zero-shuffle PV, tree reductions ----------------
// 8 waves = 4 q-subtiles x 2 kv-parities; wave owns 32 q-rows of a 128-row q-tile.
__global__ __launch_bounds__(512, 4) void attn_kernel(const bf16* __restrict__ qkv,
                                                      const bf16* __restrict__ vt,
                                                      bf16* __restrict__ O) {
  __shared__ __align__(16) unsigned char Ks[2][16384];  // [128 s][64 d] bf16
  __shared__ __align__(16) unsigned char Vs[2][16384];  // [64 d][128 s-perm] bf16
  int tid = threadIdx.x, lane = tid & 63, w = tid >> 6;
  int qw = w & 3, p = w >> 2;
  int bid = blockIdx.x;
  int xcd = bid & 7, slot = bid >> 3;
  int bh = xcd * 4 + (slot & 3);
  int u = slot >> 2;                       // 0..15, increasing with bid
  int qt = 15 - u;                         // LPT: heaviest jobs first, strictly decreasing
  int b = bh >> 4, h = bh & 15;
  int q0w = qt * 128 + qw * 32;
  int l31 = lane & 31, hi = lane >> 5;
  const char* qb = (const char*)qkv;
  const char* vb = (const char*)vt;

  int kr0 = tid >> 3, kcs = (tid & 7) ^ (kr0 & 7);
  int vr0 = tid >> 4, vcs = (tid & 15) ^ (vr0 & 7);

#define STAGE(buf, kvbase)                                                                              \
  do {                                                                                                  \
    gload_lds16(qb + (((size_t)(b * 2048 + (kvbase) + kr0) * 3072) + 1024 + h * 64) * 2 + kcs * 16,     \
                (char*)Ks[buf] + tid * 16);                                                             \
    gload_lds16(qb + (((size_t)(b * 2048 + (kvbase) + kr0 + 64) * 3072) + 1024 + h * 64) * 2 + kcs * 16,\
                (char*)Ks[buf] + (tid + 512) * 16);                                                     \
    gload_lds16(vb + (((size_t)(bh * 64 + vr0) * 2048) + (kvbase)) * 2 + vcs * 16,                      \
                (char*)Vs[buf] + tid * 16);                                                             \
    gload_lds16(vb + (((size_t)(bh * 64 + vr0 + 32) * 2048) + (kvbase)) * 2 + vcs * 16,                 \
                (char*)Vs[buf] + (tid + 512) * 16);                                                     \
  } while (0)

  // Q fragments (B-operand), scale = 1/8 * log2(e) folded (exp2 domain)
  bf16x8 aq[4];
#pragma unroll
  for (int s = 0; s < 4; s++) {
    size_t row = (size_t)(b * 2048 + q0w + l31);
    bf16x8 v = *(const bf16x8*)(qb + (row * 3072 + h * 64 + s * 16 + hi * 8) * 2);
#pragma unroll
    for (int e = 0; e < 8; e++) v[e] = (bf16)((float)v[e] * 0.18033688f);
    aq[s] = v;
  }

  // precomputed loop-invariant LDS read offsets (compile-time indexed arrays)
  int koff[8], voff[8];
#pragma unroll
  for (int s = 0; s < 4; s++)
#pragma unroll
    for (int kf = 0; kf < 2; kf++) {
      int row = p * 64 + kf * 32 + l31;
      int ch = (hi + 2 * s) ^ (row & 7);
      koff[s * 2 + kf] = row * 128 + ch * 16;
    }
#pragma unroll
  for (int kf = 0; kf < 2; kf++)
#pragma unroll
    for (int sg = 0; sg < 2; sg++)
#pragma unroll
      for (int nf = 0; nf < 2; nf++) {
        int row = nf * 32 + l31;
        int ch = ((p * 8) + (hi + 2 * sg + 4 * kf)) ^ (row & 7);
        voff[(kf * 2 + sg) * 2 + nf] = row * 256 + ch * 16;
      }

  f32x16 o0 = {}, o1 = {};
  float mrun = -3e38f, lrun = 0.f;
  int npair = qt + 1;

  STAGE(0, 0);
  asm volatile("s_waitcnt vmcnt(0)" ::: "memory");
  __builtin_amdgcn_s_barrier();

  for (int i = 0; i < npair; i++) {
    int cur = i & 1;
    if (i + 1 < npair) STAGE(cur ^ 1, (i + 1) * 128);

    int kvw = i * 128 + p * 64;
    if (kvw <= q0w + 31) {
      bool diag = (kvw + 63 > q0w);
      const char* kbase = (const char*)Ks[0] + (cur << 14);
      const char* vbase = (const char*)Vs[0] + (cur << 14);

      // S^T: C[k][q], lane col = q = q0w + l31; row k = kvw + kf*32 + crow(r,hi)
      f32x16 scr[2];
#pragma unroll
      for (int kf = 0; kf < 2; kf++)
#pragma unroll
        for (int r = 0; r < 16; r++) scr[kf][r] = 0.f;
      __builtin_amdgcn_s_setprio(1);
#pragma unroll
      for (int s = 0; s < 4; s++) {
#pragma unroll
        for (int kf = 0; kf < 2; kf++) {
          bf16x8 ak = *(const bf16x8*)(kbase + koff[s * 2 + kf]);
          scr[kf] = __builtin_amdgcn_mfma_f32_32x32x16_bf16(ak, aq[s], scr[kf], 0, 0, 0);
        }
      }
      __builtin_amdgcn_s_setprio(0);

      int qg = q0w + l31;
      if (diag) {
#pragma unroll
        for (int kf = 0; kf < 2; kf++)
#pragma unroll
          for (int r = 0; r < 16; r++) {
            int k = kvw + kf * 32 + (r & 3) + 8 * (r >> 2) + 4 * hi;
            if (k > qg) scr[kf][r] = -3e38f;
          }
      }

      // row max: tree reduce (depth 5) instead of serial chain
      float mt[16];
#pragma unroll
      for (int r = 0; r < 16; r++) mt[r] = fmaxf(scr[0][r], scr[1][r]);
#pragma unroll
      for (int s2 = 8; s2 >= 1; s2 >>= 1)
#pragma unroll
        for (int r = 0; r < s2; r++) mt[r] = fmaxf(mt[r], mt[r + s2]);
      float mx = fmaxf(mt[0], __shfl_xor(mt[0], 32));

      // T13 defer-max
      if (!__all(mx - mrun <= 11.5f)) {
        float mnew = fmaxf(mrun, mx);
        float corr = exp2f(mrun - mnew);
        mrun = mnew;
        lrun *= corr;
#pragma unroll
        for (int r = 0; r < 16; r++) {
          float cr = __shfl(corr, (r & 3) + 8 * (r >> 2) + 4 * hi);
          o0[r] *= cr; o1[r] *= cr;
        }
      }

      // P = exp2(S' - mrun); pack pairs; tree-sum
      unsigned D[2][8];
      float ps[16];
#pragma unroll
      for (int kf = 0; kf < 2; kf++)
#pragma unroll
        for (int j = 0; j < 8; j++) {
          float p0 = exp2f(scr[kf][2 * j] - mrun);
          float p1 = exp2f(scr[kf][2 * j + 1] - mrun);
          ps[kf * 8 + j] = p0 + p1;
          bf16x2 tp; tp[0] = (bf16)p0; tp[1] = (bf16)p1;
          D[kf][j] = __builtin_bit_cast(unsigned, tp);
        }
#pragma unroll
      for (int s2 = 8; s2 >= 1; s2 >>= 1)
#pragma unroll
        for (int r = 0; r < s2; r++) ps[r] += ps[r + s2];
      lrun += ps[0] + __shfl_xor(ps[0], 32);

      // PV: sigma-permuted V makes D dwords the A-fragment directly (no shuffles)
#pragma unroll
      for (int kf = 0; kf < 2; kf++) {
#pragma unroll
        for (int sg = 0; sg < 2; sg++) {
          union { unsigned u4[4]; bf16x8 v; } ap;
          ap.u4[0] = D[kf][4 * sg + 0];
          ap.u4[1] = D[kf][4 * sg + 1];
          ap.u4[2] = D[kf][4 * sg + 2];
          ap.u4[3] = D[kf][4 * sg + 3];
          __builtin_amdgcn_s_setprio(1);
#pragma unroll
          for (int nf = 0; nf < 2; nf++) {
            bf16x8 bv = *(const bf16x8*)(vbase + voff[(kf * 2 + sg) * 2 + nf]);
            if (nf == 0) o0 = __builtin_amdgcn_mfma_f32_32x32x16_bf16(ap.v, bv, o0, 0, 0, 0);
            else         o1 = __builtin_amdgcn_mfma_f32_32x32x16_bf16(ap.v, bv, o1, 0, 0, 0);
          }
          __builtin_amdgcn_s_setprio(0);
        }
      }
    }

    asm volatile("s_waitcnt vmcnt(0)" ::: "memory");
    __builtin_amdgcn_s_barrier();
  }

  // ---- cross-parity combine (reuse staging LDS) ----
  float* mlb = (float*)Ks;   // [qw][p][{m,l}][32]
  if (hi == 0) {
    mlb[((qw * 2 + p) * 2 + 0) * 32 + l31] = mrun;
    mlb[((qw * 2 + p) * 2 + 1) * 32 + l31] = lrun;
  }
  __syncthreads();
  float m_o = mlb[((qw * 2 + (1 - p)) * 2 + 0) * 32 + l31];
  float l_o = mlb[((qw * 2 + (1 - p)) * 2 + 1) * 32 + l31];
  float Mm = fmaxf(mrun, m_o);
  float cs = exp2f(mrun - Mm);
  float L  = lrun * cs + l_o * exp2f(m_o - Mm);
  float* obuf = (float*)Vs;  // [qw][32 r][64 lane]
  if (p == 1) {
#pragma unroll
    for (int r = 0; r < 16; r++) {
      int crow = (r & 3) + 8 * (r >> 2) + 4 * hi;
      float c = __shfl(cs, crow);
      obuf[qw * 2048 + r * 64 + lane]        = o0[r] * c;
      obuf[qw * 2048 + (r + 16) * 64 + lane] = o1[r] * c;
    }
  }
  __syncthreads();
  if (p == 0) {
    float linv = 1.0f / L;
#pragma unroll
    for (int r = 0; r < 16; r++) {
      int crow = (r & 3) + 8 * (r >> 2) + 4 * hi;
      float c  = __shfl(cs, crow);
      float li = __shfl(linv, crow);
      size_t row = (size_t)(b * 2048 + q0w + crow);
      float v0 = (o0[r] * c + obuf[qw * 2048 + r * 64 + lane]) * li;
      float v1 = (o1[r] * c + obuf[qw * 2048 + (r + 16) * 64 + lane]) * li;
      O[row * 1024 + h * 64 + l31]      = (bf16)v0;
      O[row * 1024 + h * 64 + 32 + l31] = (bf16)v1;
    }
  }
#undef STAGE
}

extern "C" void kernel_launch(void* const* d_in, const int* in_sizes, int n_in,
                              void* d_out, int out_size, void* d_ws, size_t ws_size,
                              hipStream_t stream) {
  const float* x      = (const float*)d_in[0];
  const float* w_qkv  = (const float*)d_in[1];
  const float* w_proj = (const float*)d_in[2];
  const float* b_proj = (const float*)d_in[3];

  char* ws = (char*)d_ws;
  size_t off = 0;
  bf16* xb     = (bf16*)(ws + off); off += (size_t)M_ * D_ * 2;
  bf16* wqkvT  = (bf16*)(ws + off); off += (size_t)N3_ * D_ * 2;
  bf16* wprojT = (bf16*)(ws + off); off += (size_t)D_ * D_ * 2;
  bf16* qkvb   = (bf16*)(ws + off); off += (size_t)M_ * N3_ * 2;
  bf16* ob     = (bf16*)(ws + off); off += (size_t)M_ * D_ * 2;
  bf16* vtb    = (bf16*)(ws + off); off += (size_t)M_ * D_ * 2;
  float* cosT  = (float*)(ws + off); off += (size_t)S_ * 32 * 4;
  float* sinT  = (float*)(ws + off); off += (size_t)S_ * 32 * 4;

  conv_f32_bf16<<<(M_ * D_ / 4 + 255) / 256, 256, 0, stream>>>(x, xb, M_ * D_ / 4);
  transpose_to_bf16<<<dim3(N3_ / 32, D_ / 32), dim3(32, 8), 0, stream>>>(w_qkv, wqkvT, D_, N3_);
  transpose_to_bf16<<<dim3(D_ / 32, D_ / 32), dim3(32, 8), 0, stream>>>(w_proj, wprojT, D_, D_);
  rope_table<<<(S_ * 32) / 256, 256, 0, stream>>>(cosT, sinT);
  gemm128<<<dim3(N3_ / 128, M_ / 128), 256, 0, stream>>>(xb, wqkvT, M_, N3_, D_, qkvb, cosT, sinT, vtb);
  attn_kernel<<<512, 512, 0, stream>>>(qkvb, vtb, ob);
  gemm_proj<<<dim3(8, 64), 256, 0, stream>>>(ob, wprojT, (float*)d_out, b_proj);
}